// Round 10
// baseline (321.458 us; speedup 1.0000x reference)
//
#include <hip/hip_runtime.h>
#include <hip/hip_fp16.h>

#define NN 100000
#define NE 1600000
#define NG 512
#define OUTS 8128
#define NB 1568     // buckets of 64 nodes (1568*64 = 100352 >= NN)
#define RUN 7       // 256*7 = 1792 >= NB, per-thread scan run
#define CHUNK 8192
#define NPB 196     // ceil(NE/CHUNK)

typedef short bf16x8 __attribute__((ext_vector_type(8)));
typedef _Float16 f16x8 __attribute__((ext_vector_type(8)));
typedef _Float16 f16x2 __attribute__((ext_vector_type(2)));
typedef float f32x4 __attribute__((ext_vector_type(4)));

__device__ __forceinline__ unsigned pack_bf16x2(float a, float b) {
    unsigned ua = __float_as_uint(a);
    unsigned ub = __float_as_uint(b);
    ua = (ua + 0x7fffu + ((ua >> 16) & 1u)) >> 16;
    ub = (ub + 0x7fffu + ((ub >> 16) & 1u)) >> 16;
    return ua | (ub << 16);
}
__device__ __forceinline__ unsigned short f2bf(float f) {
    unsigned u = __float_as_uint(f);
    u = (u + 0x7fffu + ((u >> 16) & 1u)) >> 16;
    return (unsigned short)u;
}
// f32 pair -> packed f16x2 (RTZ), as raw uint
__device__ __forceinline__ unsigned cvt_pkrtz_u(float a, float b) {
    auto h = __builtin_amdgcn_cvt_pkrtz(a, b);
    union { decltype(h) h2; unsigned u; } c; c.h2 = h; return c.u;
}
__device__ __forceinline__ f16x2 u2h(unsigned u) { union { unsigned u; f16x2 h; } c; c.u = u; return c.h; }

// e4m3 encode for f >= 0 (relu'd): e4m3(v) == f16(v/256) with 10->3 mantissa round
__device__ __forceinline__ unsigned f2fp8(float f) {
    unsigned h = (unsigned)__half_as_ushort(__float2half(f * 0.00390625f));
    return (h + 0x3Fu + ((h >> 7) & 1u)) >> 7;
}

// ---- phase 1: partition an 8192-edge chunk into 1568 fine buckets (LDS atomics only) ----
__global__ __launch_bounds__(256) void k_part(const int* __restrict__ src, const int* __restrict__ dst,
        int* __restrict__ tmp, int* __restrict__ scanhist) {
    __shared__ int hist[NB];
    __shared__ int scan[256];
    int p = blockIdx.x, t = threadIdx.x;
    int e0 = p * CHUNK;
    int e1 = min(e0 + CHUNK, NE);
    for (int i = t; i < NB; i += 256) hist[i] = 0;
    __syncthreads();
    for (int e = e0 + t; e < e1; e += 256)
        atomicAdd(&hist[dst[e] >> 6], 1);
    __syncthreads();
    int loc[RUN];
    int s = 0;
    #pragma unroll
    for (int k = 0; k < RUN; ++k) {
        int idx = t * RUN + k;
        int v = (idx < NB) ? hist[idx] : 0;
        loc[k] = s; s += v;
    }
    scan[t] = s;
    __syncthreads();
    for (int off = 1; off < 256; off <<= 1) {
        int v = (t >= off) ? scan[t - off] : 0;
        __syncthreads();
        scan[t] += v;
        __syncthreads();
    }
    int excl = scan[t] - s;
    #pragma unroll
    for (int k = 0; k < RUN; ++k) {
        int idx = t * RUN + k;
        if (idx < NB) {
            int o = excl + loc[k];
            hist[idx] = o;                       // reuse hist as cursor
            scanhist[p * (NB + 1) + idx] = o;
        }
    }
    if (t == 0) scanhist[p * (NB + 1) + NB] = e1 - e0;
    __syncthreads();
    for (int e = e0 + t; e < e1; e += 256) {
        int d = dst[e];
        int b = d >> 6;
        int r = atomicAdd(&hist[b], 1);          // LDS atomic only
        tmp[e0 + r] = (src[e] << 6) | (d & 63);
    }
}

// ---- per-bucket totals (parallel) ----
__global__ __launch_bounds__(256) void k_btotA(const int* __restrict__ scanhist, int* __restrict__ btot) {
    int b = blockIdx.x * 256 + threadIdx.x;
    if (b >= NB) return;
    int tot = 0;
    for (int p = 0; p < NPB; ++p) {
        const int* row = scanhist + p * (NB + 1);
        tot += row[b + 1] - row[b];
    }
    btot[b] = tot;
}

// ---- scan bucket totals -> bucketbase (1 block) ----
__global__ __launch_bounds__(256) void k_btotB(const int* __restrict__ btot, int* __restrict__ bucketbase) {
    __shared__ int scan[256];
    int t = threadIdx.x;
    int loc[RUN];
    int s = 0;
    #pragma unroll
    for (int k = 0; k < RUN; ++k) {
        int idx = t * RUN + k;
        int v = (idx < NB) ? btot[idx] : 0;
        loc[k] = s; s += v;
    }
    scan[t] = s;
    __syncthreads();
    for (int off = 1; off < 256; off <<= 1) {
        int v = (t >= off) ? scan[t - off] : 0;
        __syncthreads();
        scan[t] += v;
        __syncthreads();
    }
    int excl = scan[t] - s;
    #pragma unroll
    for (int k = 0; k < RUN; ++k) {
        int idx = t * RUN + k;
        if (idx < NB) bucketbase[idx] = excl + loc[k];
    }
}

// ---- phase 2: per-bucket (64 nodes) count + scan + place; emits cnti/rowptr/dinv/colidx ----
__global__ __launch_bounds__(256) void k_fill2(const int* __restrict__ bucketbase,
        const int* __restrict__ scanhist, const int* __restrict__ tmp,
        int* __restrict__ colidx, int* __restrict__ cnti, int* __restrict__ rowptr,
        float* __restrict__ dinv) {
    __shared__ int lc[64], rb[64], sc[64];
    int b = blockIdx.x, t = threadIdx.x;
    int n0 = b << 6;
    if (t < 64) lc[t] = 0;
    __syncthreads();
    int w = t >> 6, lane = t & 63;
    // count phase
    for (int p = w; p < NPB; p += 4) {
        int s0 = scanhist[p * (NB + 1) + b];
        int s1 = scanhist[p * (NB + 1) + b + 1];
        int base = p * CHUNK;
        for (int i = s0 + lane; i < s1; i += 64)
            atomicAdd(&lc[tmp[base + i] & 63], 1);
    }
    __syncthreads();
    int v = (t < 64) ? lc[t] : 0;
    if (t < 64) sc[t] = v;
    __syncthreads();
    for (int off = 1; off < 64; off <<= 1) {
        int x = (t < 64 && t >= off) ? sc[t - off] : 0;
        __syncthreads();
        if (t < 64) sc[t] += x;
        __syncthreads();
    }
    if (t < 64) {
        int excl = sc[t] - v;
        int base0 = bucketbase[b];
        rb[t] = base0 + excl;
        int node = n0 + t;
        if (node < NN) {
            cnti[node] = v;
            rowptr[node] = base0 + excl;
            dinv[node] = rsqrtf((float)v + 1.0f);
        }
        lc[t] = 0;
    }
    __syncthreads();
    // place phase
    for (int p = w; p < NPB; p += 4) {
        int s0 = scanhist[p * (NB + 1) + b];
        int s1 = scanhist[p * (NB + 1) + b + 1];
        int base = p * CHUNK;
        for (int i = s0 + lane; i < s1; i += 64) {
            int vv = tmp[base + i];
            int dl = vv & 63;
            int pos = atomicAdd(&lc[dl], 1);     // LDS atomic only
            colidx[rb[dl] + pos] = vv >> 6;
        }
    }
}

// ---- segment ends from sorted batch ----
__global__ __launch_bounds__(256) void k_segend(const int* __restrict__ batch, int* __restrict__ seg_end) {
    int i = blockIdx.x * 256 + threadIdx.x;
    if (i >= NN) return;
    int b = batch[i];
    int bn = (i == NN - 1) ? NG : batch[i + 1];
    for (int g = b; g < bn; ++g) seg_end[g] = i + 1;
    if (i == 0) {
        for (int g = 0; g < b; ++g) seg_end[g] = 0;
    }
}

// ---- W[K][128] fp32 -> WT[128][K]; F16=1 -> f16 bits, else bf16 ----
template<int K, int F16>
__global__ __launch_bounds__(256) void k_wt(const float* __restrict__ W, unsigned short* __restrict__ wt) {
    int e = blockIdx.x * 256 + threadIdx.x;
    int n = e / K, k = e - n * K;
    float v = W[k * 128 + n];
    wt[e] = F16 ? (unsigned short)__half_as_ushort(__float2half(v)) : f2bf(v);
}

// ---- D3 fp32 -> bf16 (same layout) ----
__global__ __launch_bounds__(256) void k_wt3(const float* __restrict__ W, unsigned short* __restrict__ o) {
    int i = blockIdx.x * 256 + threadIdx.x;
    if (i < 128 * OUTS) o[i] = f2bf(W[i]);
}

// ---- u1 = f16(x * dinv[row]), 64ch ----
__global__ __launch_bounds__(256) void k_scale_x(const float* __restrict__ x,
        const float* __restrict__ dinv, unsigned* __restrict__ u1) {
    int i = blockIdx.x * 256 + threadIdx.x;   // < NN*32
    int row = i >> 5, c = i & 31;
    float2 v = *(const float2*)&x[(long)row * 64 + c * 2];
    float d = dinv[row];
    u1[i] = cvt_pkrtz_u(v.x * d, v.y * d);
}

// ---- gather1: s1 = f16(dinv_n * (u1[n] + sum u1[src])), 64ch f16 ----
// 16 lanes/node, uint2 (4ch) per lane, 4-deep neighbor unroll
__global__ __launch_bounds__(256) void k_gather1(const int* __restrict__ rowptr,
        const int* __restrict__ cnti, const int* __restrict__ colidx,
        const unsigned* __restrict__ u, const float* __restrict__ dinv,
        unsigned* __restrict__ s1) {
    int node = blockIdx.x * 16 + (threadIdx.x >> 4);
    int lane = threadIdx.x & 15;
    const uint2* uf = (const uint2*)u;          // row = 16 uint2
    uint2 self = uf[node * 16 + lane];
    f16x2 a0 = u2h(self.x), a1 = u2h(self.y);
    f16x2 b0 = {(_Float16)0.f, (_Float16)0.f}, b1 = b0;
    f16x2 c0 = b0, c1 = b0, d0 = b0, d1 = b0;
    int n = cnti[node];
    const int* ci = colidx + rowptr[node];
    int j = 0;
    for (; j + 4 <= n; j += 4) {
        uint2 va = uf[ci[j] * 16 + lane];
        uint2 vb = uf[ci[j + 1] * 16 + lane];
        uint2 vc = uf[ci[j + 2] * 16 + lane];
        uint2 vd = uf[ci[j + 3] * 16 + lane];
        a0 += u2h(va.x); a1 += u2h(va.y);
        b0 += u2h(vb.x); b1 += u2h(vb.y);
        c0 += u2h(vc.x); c1 += u2h(vc.y);
        d0 += u2h(vd.x); d1 += u2h(vd.y);
    }
    for (; j < n; ++j) {
        uint2 va = uf[ci[j] * 16 + lane];
        a0 += u2h(va.x); a1 += u2h(va.y);
    }
    a0 += b0 + c0 + d0;
    a1 += b1 + c1 + d1;
    float d = dinv[node];
    uint2 o;
    o.x = cvt_pkrtz_u((float)a0[0] * d, (float)a0[1] * d);
    o.y = cvt_pkrtz_u((float)a1[0] * d, (float)a1[1] * d);
    *(uint2*)&s1[node * 32 + lane * 2] = o;
}

// ---- gather2: s2 = bf16(16*dinv_n * sum fp8rows), 128ch fp8 ----
// 16 lanes/node, uint2 (8ch) per lane, 4-deep unroll, sign-free packed decode
__global__ __launch_bounds__(256) void k_gather2(const int* __restrict__ rowptr,
        const int* __restrict__ cnti, const int* __restrict__ colidx,
        const unsigned* __restrict__ u, const float* __restrict__ dinv,
        unsigned* __restrict__ s2) {
    int node = blockIdx.x * 16 + (threadIdx.x >> 4);
    int lane = threadIdx.x & 15;
    const uint2* uf = (const uint2*)u;          // row = 16 uint2 (128 fp8)
    uint2 self = uf[node * 16 + lane];
    f16x2 xa = u2h((self.x & 0x007f007fu) << 7);   // c0,c2
    f16x2 xb = u2h((self.x & 0x7f007f00u) >> 1);   // c1,c3
    f16x2 ya = u2h((self.y & 0x007f007fu) << 7);   // c4,c6
    f16x2 yb = u2h((self.y & 0x7f007f00u) >> 1);   // c5,c7
    f16x2 z = {(_Float16)0.f, (_Float16)0.f};
    f16x2 xa2 = z, xb2 = z, ya2 = z, yb2 = z;
    int n = cnti[node];
    const int* ci = colidx + rowptr[node];
    int j = 0;
    for (; j + 4 <= n; j += 4) {
        uint2 va = uf[ci[j] * 16 + lane];
        uint2 vb = uf[ci[j + 1] * 16 + lane];
        uint2 vc = uf[ci[j + 2] * 16 + lane];
        uint2 vd = uf[ci[j + 3] * 16 + lane];
        xa  += u2h((va.x & 0x007f007fu) << 7);  xb  += u2h((va.x & 0x7f007f00u) >> 1);
        ya  += u2h((va.y & 0x007f007fu) << 7);  yb  += u2h((va.y & 0x7f007f00u) >> 1);
        xa2 += u2h((vb.x & 0x007f007fu) << 7);  xb2 += u2h((vb.x & 0x7f007f00u) >> 1);
        ya2 += u2h((vb.y & 0x007f007fu) << 7);  yb2 += u2h((vb.y & 0x7f007f00u) >> 1);
        xa  += u2h((vc.x & 0x007f007fu) << 7);  xb  += u2h((vc.x & 0x7f007f00u) >> 1);
        ya  += u2h((vc.y & 0x007f007fu) << 7);  yb  += u2h((vc.y & 0x7f007f00u) >> 1);
        xa2 += u2h((vd.x & 0x007f007fu) << 7);  xb2 += u2h((vd.x & 0x7f007f00u) >> 1);
        ya2 += u2h((vd.y & 0x007f007fu) << 7);  yb2 += u2h((vd.y & 0x7f007f00u) >> 1);
    }
    for (; j < n; ++j) {
        uint2 va = uf[ci[j] * 16 + lane];
        xa += u2h((va.x & 0x007f007fu) << 7);  xb += u2h((va.x & 0x7f007f00u) >> 1);
        ya += u2h((va.y & 0x007f007fu) << 7);  yb += u2h((va.y & 0x7f007f00u) >> 1);
    }
    xa += xa2; xb += xb2; ya += ya2; yb += yb2;
    float d = dinv[node] * 16.0f;   // *256 (decode) / 16 (encode scale)
    uint4 o;
    o.x = pack_bf16x2((float)xa[0] * d, (float)xb[0] * d);   // c0,c1
    o.y = pack_bf16x2((float)xa[1] * d, (float)xb[1] * d);   // c2,c3
    o.z = pack_bf16x2((float)ya[0] * d, (float)yb[0] * d);   // c4,c5
    o.w = pack_bf16x2((float)ya[1] * d, (float)yb[1] * d);   // c6,c7
    *(uint4*)&s2[node * 64 + lane * 4] = o;
}

// ---- MFMA GEMM: h = relu(A@W + bias); AF16: f16 inputs; EPI 0: out fp8(16*dinv*h); 1: bf16 ----
template<int K, int EPI, int AF16>
__global__ __launch_bounds__(256) void k_gemm_mfma(const unsigned short* __restrict__ Ab,
        const unsigned short* __restrict__ wt, const float* __restrict__ dinv,
        const float* __restrict__ bias, void* __restrict__ outp) {
    constexpr int KS = K / 32;
    constexpr int SLOTS = K / 8;
    __shared__ __align__(16) unsigned short wlds[128 * K];
    char* lb = (char*)wlds;
    for (int c = threadIdx.x; c < 128 * SLOTS; c += 256) {
        int n = c / SLOTS, s = c - n * SLOTS;
        *(uint4*)(lb + n * (2 * K) + ((s ^ (n & 7)) << 4)) = *(const uint4*)(wt + c * 8);
    }
    __syncthreads();
    int lane = threadIdx.x & 63;
    int w = threadIdx.x >> 6;
    int r0 = blockIdx.x * 64 + w * 16;
    int arow = r0 + (lane & 15);
    if (arow >= NN) arow = NN - 1;
    bf16x8 af[KS];
    #pragma unroll
    for (int ks = 0; ks < KS; ++ks)
        af[ks] = *(const bf16x8*)&Ab[(long)arow * K + ks * 32 + (lane >> 4) * 8];
    f32x4 acc[8];
    #pragma unroll
    for (int t = 0; t < 8; ++t) acc[t] = (f32x4){0.f, 0.f, 0.f, 0.f};
    #pragma unroll
    for (int ks = 0; ks < KS; ++ks) {
        #pragma unroll
        for (int t = 0; t < 8; ++t) {
            int n = t * 16 + (lane & 15);
            int slot = ks * 4 + (lane >> 4);
            bf16x8 braw = *(const bf16x8*)(lb + n * (2 * K) + ((slot ^ (n & 7)) << 4));
            if constexpr (AF16) {
                union { bf16x8 r; f16x8 h; } ca, cb;
                ca.r = af[ks]; cb.r = braw;
                acc[t] = __builtin_amdgcn_mfma_f32_16x16x32_f16(ca.h, cb.h, acc[t], 0, 0, 0);
            } else {
                acc[t] = __builtin_amdgcn_mfma_f32_16x16x32_bf16(af[ks], braw, acc[t], 0, 0, 0);
            }
        }
    }
    float bv[8];
    #pragma unroll
    for (int t = 0; t < 8; ++t) bv[t] = bias[t * 16 + (lane & 15)];
    #pragma unroll
    for (int r = 0; r < 4; ++r) {
        long row = r0 + (lane >> 4) * 4 + r;
        if (row >= NN) continue;
        float d = dinv[row];
        #pragma unroll
        for (int t = 0; t < 8; ++t) {
            float val = fmaxf(acc[t][r] + bv[t], 0.f);
            int col = t * 16 + (lane & 15);
            if (EPI == 0)
                ((unsigned char*)outp)[row * 128 + col] = (unsigned char)f2fp8(val * (16.0f * d));
            else
                ((unsigned short*)outp)[row * 128 + col] = f2bf(val);
        }
    }
}

// ---- segmented mean pool over bf16 h2: 4 waves per graph ----
__global__ __launch_bounds__(256) void k_poolmean(const unsigned* __restrict__ h,
        const int* __restrict__ seg_end, float* __restrict__ hg) {
    __shared__ float part[3][128];
    int g = blockIdx.x;
    int w = threadIdx.x >> 6, t = threadIdx.x & 63;
    int s = (g == 0) ? 0 : seg_end[g - 1];
    int e = seg_end[g];
    float a0 = 0.f, a1 = 0.f;
    for (int i = s + w; i < e; i += 4) {
        unsigned u = h[(long)i * 64 + t];
        a0 += __uint_as_float(u << 16);
        a1 += __uint_as_float(u & 0xffff0000u);
    }
    if (w) { part[w - 1][t * 2] = a0; part[w - 1][t * 2 + 1] = a1; }
    __syncthreads();
    if (w == 0) {
        a0 += part[0][t * 2] + part[1][t * 2] + part[2][t * 2];
        a1 += part[0][t * 2 + 1] + part[1][t * 2 + 1] + part[2][t * 2 + 1];
        float inv = (e > s) ? 1.0f / (float)(e - s) : 0.f;
        float2 o = { a0 * inv, a1 * inv };
        *(float2*)&hg[g * 128 + t * 2] = o;
    }
}

// ---- mu/logvar heads + reparameterise ----
__global__ __launch_bounds__(64) void k_head(const float* __restrict__ hg,
        const float* __restrict__ Wmu, const float* __restrict__ bmu,
        const float* __restrict__ Wlv, const float* __restrict__ blv,
        const float* __restrict__ eps, float* __restrict__ mu_o, float* __restrict__ lv_o,
        float* __restrict__ z) {
    __shared__ float row[128];
    int g = blockIdx.x, t = threadIdx.x;
    row[t]      = hg[g * 128 + t];
    row[t + 64] = hg[g * 128 + t + 64];
    __syncthreads();
    float mu = bmu[t], lv = blv[t];
    for (int k = 0; k < 128; ++k) {
        float rv = row[k];
        mu += rv * Wmu[k * 64 + t];
        lv += rv * Wlv[k * 64 + t];
    }
    mu_o[g * 64 + t] = mu;
    lv_o[g * 64 + t] = lv;
    z[g * 64 + t] = mu + eps[g * 64 + t] * expf(0.5f * lv);
}

// ---- small MLP layer ----
__global__ __launch_bounds__(128) void k_mlp(const float* __restrict__ A, int K,
        const float* __restrict__ W, const float* __restrict__ b, float* __restrict__ out) {
    __shared__ float row[128];
    int m = blockIdx.x, t = threadIdx.x;
    if (t < K) row[t] = A[m * K + t];
    __syncthreads();
    float acc = b[t];
    for (int k = 0; k < K; ++k) acc += row[k] * W[k * 128 + t];
    out[m * 128 + t] = fmaxf(acc, 0.f);
}

// ---- probs = sigmoid(A @ D3_bf16 + d3); 16-row m-tiles, packed bf16 W decode ----
__global__ __launch_bounds__(256) void k_dec3(const float* __restrict__ A,
        const unsigned short* __restrict__ Wb, const float* __restrict__ b, float* __restrict__ out) {
    __shared__ float alds[16][128];
    int m0 = blockIdx.y * 16;
    for (int i = threadIdx.x; i < 16 * 128; i += 256)
        alds[i >> 7][i & 127] = A[(m0 + (i >> 7)) * 128 + (i & 127)];
    __syncthreads();
    if (threadIdx.x >= 254) return;
    int c = blockIdx.x * 1016 + threadIdx.x * 4;
    float4 bb = *(const float4*)&b[c];
    float4 acc[16];
    #pragma unroll
    for (int r = 0; r < 16; ++r) acc[r] = bb;
    for (int k = 0; k < 128; ++k) {
        uint2 u = *(const uint2*)&Wb[(long)k * OUTS + c];
        float w0 = __uint_as_float(u.x << 16);
        float w1 = __uint_as_float(u.x & 0xffff0000u);
        float w2 = __uint_as_float(u.y << 16);
        float w3 = __uint_as_float(u.y & 0xffff0000u);
        #pragma unroll
        for (int r = 0; r < 16; ++r) {
            float a = alds[r][k];
            acc[r].x += a * w0; acc[r].y += a * w1;
            acc[r].z += a * w2; acc[r].w += a * w3;
        }
    }
    #pragma unroll
    for (int r = 0; r < 16; ++r) {
        float4 o;
        o.x = 1.f / (1.f + expf(-acc[r].x));
        o.y = 1.f / (1.f + expf(-acc[r].y));
        o.z = 1.f / (1.f + expf(-acc[r].z));
        o.w = 1.f / (1.f + expf(-acc[r].w));
        *(float4*)&out[(long)(m0 + r) * OUTS + c] = o;
    }
}

// ---- build symmetric adjacency ----
__global__ __launch_bounds__(256) void k_adj(const float* __restrict__ probs, float* __restrict__ adj) {
    int t = blockIdx.x * 256 + threadIdx.x;
    int g = t >> 12;
    int rem = t & 4095;
    int r = rem >> 5;
    int c0 = (rem & 31) * 4;
    const float* pg = &probs[g * OUTS];
    float4 o;
    float* op = (float*)&o;
    #pragma unroll
    for (int j = 0; j < 4; ++j) {
        int c = c0 + j;
        if (c == r) { op[j] = 0.f; continue; }
        int a = c < r ? c : r;
        int b = c < r ? r : c;
        int k = a * (255 - a) / 2 + (b - a - 1);
        op[j] = pg[k];
    }
    *(float4*)&adj[(long)t * 4] = o;
}

extern "C" void kernel_launch(void* const* d_in, const int* in_sizes, int n_in,
                              void* d_out, int out_size, void* d_ws, size_t ws_size,
                              hipStream_t stream) {
    const float* x   = (const float*)d_in[0];
    const int*   ei  = (const int*)d_in[1];
    const int* batch = (const int*)d_in[2];
    const float* eps = (const float*)d_in[3];
    const float* W1  = (const float*)d_in[4];
    const float* b1  = (const float*)d_in[5];
    const float* W2  = (const float*)d_in[6];
    const float* b2  = (const float*)d_in[7];
    const float* Wmu = (const float*)d_in[8];
    const float* bmu = (const float*)d_in[9];
    const float* Wlv = (const float*)d_in[10];
    const float* blv = (const float*)d_in[11];
    const float* D1  = (const float*)d_in[12];
    const float* d1  = (const float*)d_in[13];
    const float* D2  = (const float*)d_in[14];
    const float* d2  = (const float*)d_in[15];
    const float* D3  = (const float*)d_in[16];
    const float* d3  = (const float*)d_in[17];

    const int* esrc = ei;
    const int* edst = ei + NE;

    float* out  = (float*)d_out;
    float* mu_o = out + 8388608;
    float* lv_o = mu_o + 32768;

    // --- CSR + small scratch in d_out (region fully overwritten by k_adj at the end) ---
    int*   colidx   = (int*)out;                  // 1,600,000
    int*   cnti     = colidx + 1600000;           // 100,000
    int*   rowptr   = cnti + 100000;              // 100,000
    int*   seg_end  = rowptr + 100000;            // 512
    float* dinv     = (float*)(seg_end + 512);    // 100,000
    int*   scanhist = (int*)(dinv + 100000);      // 196*1569 = 307,524
    int*   bucketbase = scanhist + 307524;        // 1568
    int*   btot     = bucketbase + 1568;          // 1568
    unsigned short* wt3 = (unsigned short*)(btot + 1568);  // 1,040,384 u16 (ends ~2.73M floats << 8.39M)

    // --- ws layout (float-unit offsets) ---
    float* ws = (float*)d_ws;
    unsigned* u1u = (unsigned*)ws;                         // 3.2M uints (f16x2)
    unsigned* s1u = u1u + 3200000;                         // 3.2M uints (f16x2)
    unsigned char* u2b = (unsigned char*)(ws + 6400000);   // 12.8M bytes (fp8)
    unsigned* s2u = (unsigned*)(ws + 9600000);             // 6.4M uints (bf16x2)
    unsigned* h2b = (unsigned*)(ws + 16000000);            // 6.4M uints (bf16x2)
    unsigned short* wt1 = (unsigned short*)(ws + 22400000);   // 8192 u16 (f16)
    unsigned short* wt2 = wt1 + 8192;                         // 16384 u16 (bf16)
    int* tmp = (int*)(ws + 22420000);                      // 1.6M+ ints
    // decoder scratch aliases u1/s1 (dead after gemm1)
    float* hg    = ws;
    float* zbuf  = hg + 65536;
    float* p1    = zbuf + 32768;
    float* p2    = p1 + 65536;
    float* probs = p2 + 65536;

    // ---- CSR build: zero global atomics, 1568-way parallel fill ----
    k_part<<<NPB, 256, 0, stream>>>(esrc, edst, tmp, scanhist);
    k_btotA<<<(NB + 255) / 256, 256, 0, stream>>>(scanhist, btot);
    k_btotB<<<1, 256, 0, stream>>>(btot, bucketbase);
    k_fill2<<<NB, 256, 0, stream>>>(bucketbase, scanhist, tmp, colidx, cnti, rowptr, dinv);
    k_segend<<<(NN + 255) / 256, 256, 0, stream>>>(batch, seg_end);

    // ---- weights: wt1 f16, wt2 bf16 (transposed), D3 bf16 ----
    k_wt<64, 1><<<32, 256, 0, stream>>>(W1, wt1);
    k_wt<128, 0><<<64, 256, 0, stream>>>(W2, wt2);
    k_wt3<<<(128 * OUTS + 255) / 256, 256, 0, stream>>>(D3, wt3);

    // ---- conv1 (f16 gather in 64-ch x-space, then f16 MFMA GEMM -> fp8) ----
    k_scale_x<<<12500, 256, 0, stream>>>(x, dinv, u1u);
    k_gather1<<<6250, 256, 0, stream>>>(rowptr, cnti, colidx, u1u, dinv, s1u);
    k_gemm_mfma<64, 0, 1><<<1563, 256, 0, stream>>>((const unsigned short*)s1u, wt1, dinv, b1, u2b);

    // ---- conv2 (fp8 packed-decode gather, then bf16 MFMA GEMM) ----
    k_gather2<<<6250, 256, 0, stream>>>(rowptr, cnti, colidx, (const unsigned*)u2b, dinv, s2u);
    k_gemm_mfma<128, 1, 0><<<1563, 256, 0, stream>>>((const unsigned short*)s2u, wt2, dinv, b2, h2b);

    // ---- pool + heads ----
    k_poolmean<<<NG, 256, 0, stream>>>(h2b, seg_end, hg);
    k_head<<<NG, 64, 0, stream>>>(hg, Wmu, bmu, Wlv, blv, eps, mu_o, lv_o, zbuf);

    // ---- decoder ----
    k_mlp<<<NG, 128, 0, stream>>>(zbuf, 64, D1, d1, p1);
    k_mlp<<<NG, 128, 0, stream>>>(p1, 128, D2, d2, p2);
    dim3 g3(8, 32);
    k_dec3<<<g3, 256, 0, stream>>>(p2, wt3, d3, probs);
    k_adj<<<8192, 256, 0, stream>>>(probs, out);
}

// Round 11
// 258.631 us; speedup vs baseline: 1.2429x; 1.2429x over previous
//
#include <hip/hip_runtime.h>
#include <hip/hip_fp16.h>

#define NN 100000
#define NE 1600000
#define NG 512
#define OUTS 8128
#define NB2 196     // coarse buckets of 512 nodes (196*512 = 100352 >= NN)
#define CHUNK 8192
#define NPB 196     // ceil(NE/CHUNK)

typedef short bf16x8 __attribute__((ext_vector_type(8)));
typedef _Float16 f16x8 __attribute__((ext_vector_type(8)));
typedef _Float16 f16x2 __attribute__((ext_vector_type(2)));
typedef float f32x4 __attribute__((ext_vector_type(4)));

__device__ __forceinline__ unsigned pack_bf16x2(float a, float b) {
    unsigned ua = __float_as_uint(a);
    unsigned ub = __float_as_uint(b);
    ua = (ua + 0x7fffu + ((ua >> 16) & 1u)) >> 16;
    ub = (ub + 0x7fffu + ((ub >> 16) & 1u)) >> 16;
    return ua | (ub << 16);
}
__device__ __forceinline__ unsigned short f2bf(float f) {
    unsigned u = __float_as_uint(f);
    u = (u + 0x7fffu + ((u >> 16) & 1u)) >> 16;
    return (unsigned short)u;
}
// f32 pair -> packed f16x2 (RTZ), as raw uint
__device__ __forceinline__ unsigned cvt_pkrtz_u(float a, float b) {
    auto h = __builtin_amdgcn_cvt_pkrtz(a, b);
    union { decltype(h) h2; unsigned u; } c; c.h2 = h; return c.u;
}
__device__ __forceinline__ f16x2 u2h(unsigned u) { union { unsigned u; f16x2 h; } c; c.u = u; return c.h; }

// e4m3 encode for f >= 0 (relu'd): e4m3(v) == f16(v/256) with 10->3 mantissa round
__device__ __forceinline__ unsigned f2fp8(float f) {
    unsigned h = (unsigned)__half_as_ushort(__float2half(f * 0.00390625f));
    return (h + 0x3Fu + ((h >> 7) & 1u)) >> 7;
}

// ---- phase 1: partition an 8192-edge chunk into 196 coarse buckets (512 threads) ----
__global__ __launch_bounds__(512) void k_part(const int* __restrict__ src, const int* __restrict__ dst,
        int* __restrict__ tmp, int* __restrict__ scanhist) {
    __shared__ int hist[NB2], cur[NB2], scan[256];
    int p = blockIdx.x, t = threadIdx.x;
    int e0 = p * CHUNK;
    int e1 = min(e0 + CHUNK, NE);
    for (int i = t; i < NB2; i += 512) hist[i] = 0;
    __syncthreads();
    for (int e = e0 + t; e < e1; e += 512)
        atomicAdd(&hist[dst[e] >> 9], 1);
    __syncthreads();
    int h = 0;
    if (t < 256) { h = (t < NB2) ? hist[t] : 0; scan[t] = h; }
    __syncthreads();
    for (int off = 1; off < 256; off <<= 1) {
        int v = (t < 256 && t >= off) ? scan[t - off] : 0;
        __syncthreads();
        if (t < 256) scan[t] += v;
        __syncthreads();
    }
    if (t < NB2) {
        int excl = scan[t] - h;
        cur[t] = excl;
        scanhist[p * (NB2 + 1) + t] = excl;
    }
    if (t == 0) scanhist[p * (NB2 + 1) + NB2] = e1 - e0;
    __syncthreads();
    for (int e = e0 + t; e < e1; e += 512) {
        int d = dst[e];
        int b = d >> 9;
        int r = atomicAdd(&cur[b], 1);          // LDS atomic only
        tmp[e0 + r] = (src[e] << 9) | (d & 511);
    }
}

// ---- bucket totals + exclusive scan -> bucketbase (1 block) ----
__global__ __launch_bounds__(256) void k_btot(const int* __restrict__ scanhist, int* __restrict__ bucketbase) {
    __shared__ int sc[256];
    int b = threadIdx.x;
    int tot = 0;
    if (b < NB2) {
        for (int p = 0; p < NPB; ++p)
            tot += scanhist[p * (NB2 + 1) + b + 1] - scanhist[p * (NB2 + 1) + b];
    }
    sc[b] = tot;
    __syncthreads();
    for (int off = 1; off < 256; off <<= 1) {
        int v = (b >= off) ? sc[b - off] : 0;
        __syncthreads();
        sc[b] += v;
        __syncthreads();
    }
    if (b < NB2) bucketbase[b] = sc[b] - tot;
}

// ---- phase 2: per-bucket count + scan + place (1024 threads, 16 waves) ----
__global__ __launch_bounds__(1024) void k_fill2(const int* __restrict__ bucketbase,
        const int* __restrict__ scanhist, const int* __restrict__ tmp,
        int* __restrict__ colidx, int* __restrict__ cnti, int* __restrict__ rowptr,
        float* __restrict__ dinv) {
    __shared__ int lc[512], rb[512], sc[256];
    int b = blockIdx.x, t = threadIdx.x;
    int n0 = b << 9;
    if (t < 512) lc[t] = 0;
    __syncthreads();
    int w = t >> 6, lane = t & 63;              // w in 0..15
    // count phase
    for (int p = w; p < NPB; p += 16) {
        int s0 = scanhist[p * (NB2 + 1) + b];
        int s1 = scanhist[p * (NB2 + 1) + b + 1];
        int base = p * CHUNK;
        for (int i = s0 + lane; i < s1; i += 64)
            atomicAdd(&lc[tmp[base + i] & 511], 1);
    }
    __syncthreads();
    // scan 512 via 256 pair-partials
    int v0 = 0, v1 = 0, s = 0;
    if (t < 256) { v0 = lc[2 * t]; v1 = lc[2 * t + 1]; s = v0 + v1; sc[t] = s; }
    __syncthreads();
    for (int off = 1; off < 256; off <<= 1) {
        int x = (t < 256 && t >= off) ? sc[t - off] : 0;
        __syncthreads();
        if (t < 256) sc[t] += x;
        __syncthreads();
    }
    if (t < 256) {
        int excl = sc[t] - s;
        int base0 = bucketbase[b];
        rb[2 * t] = base0 + excl;
        rb[2 * t + 1] = base0 + excl + v0;
        int node0 = n0 + 2 * t;
        if (node0 < NN) {
            cnti[node0] = v0;
            rowptr[node0] = base0 + excl;
            dinv[node0] = rsqrtf((float)v0 + 1.0f);
        }
        if (node0 + 1 < NN) {
            cnti[node0 + 1] = v1;
            rowptr[node0 + 1] = base0 + excl + v0;
            dinv[node0 + 1] = rsqrtf((float)v1 + 1.0f);
        }
    }
    __syncthreads();
    if (t < 512) lc[t] = 0;
    __syncthreads();
    // place phase
    for (int p = w; p < NPB; p += 16) {
        int s0 = scanhist[p * (NB2 + 1) + b];
        int s1 = scanhist[p * (NB2 + 1) + b + 1];
        int base = p * CHUNK;
        for (int i = s0 + lane; i < s1; i += 64) {
            int v = tmp[base + i];
            int dl = v & 511;
            int pos = atomicAdd(&lc[dl], 1);    // LDS atomic only
            colidx[rb[dl] + pos] = v >> 9;
        }
    }
}

// ---- segment ends from sorted batch ----
__global__ __launch_bounds__(256) void k_segend(const int* __restrict__ batch, int* __restrict__ seg_end) {
    int i = blockIdx.x * 256 + threadIdx.x;
    if (i >= NN) return;
    int b = batch[i];
    int bn = (i == NN - 1) ? NG : batch[i + 1];
    for (int g = b; g < bn; ++g) seg_end[g] = i + 1;
    if (i == 0) {
        for (int g = 0; g < b; ++g) seg_end[g] = 0;
    }
}

// ---- W[K][128] fp32 -> WT[128][K]; F16=1 -> f16 bits, else bf16 ----
template<int K, int F16>
__global__ __launch_bounds__(256) void k_wt(const float* __restrict__ W, unsigned short* __restrict__ wt) {
    int e = blockIdx.x * 256 + threadIdx.x;
    int n = e / K, k = e - n * K;
    float v = W[k * 128 + n];
    wt[e] = F16 ? (unsigned short)__half_as_ushort(__float2half(v)) : f2bf(v);
}

// ---- D3 fp32 -> bf16 (same layout) ----
__global__ __launch_bounds__(256) void k_wt3(const float* __restrict__ W, unsigned short* __restrict__ o) {
    int i = blockIdx.x * 256 + threadIdx.x;
    if (i < 128 * OUTS) o[i] = f2bf(W[i]);
}

// ---- u1 = f16(x * dinv[row]), 64ch ----
__global__ __launch_bounds__(256) void k_scale_x(const float* __restrict__ x,
        const float* __restrict__ dinv, unsigned* __restrict__ u1) {
    int i = blockIdx.x * 256 + threadIdx.x;   // < NN*32
    int row = i >> 5, c = i & 31;
    float2 v = *(const float2*)&x[(long)row * 64 + c * 2];
    float d = dinv[row];
    u1[i] = cvt_pkrtz_u(v.x * d, v.y * d);
}

// ---- gather1: s1 = f16(dinv_n * (u1[n] + sum u1[src])), 64ch f16 ----
// 16 lanes/node, uint2 (4ch) per lane, 4-deep neighbor unroll
__global__ __launch_bounds__(256) void k_gather1(const int* __restrict__ rowptr,
        const int* __restrict__ cnti, const int* __restrict__ colidx,
        const unsigned* __restrict__ u, const float* __restrict__ dinv,
        unsigned* __restrict__ s1) {
    int node = blockIdx.x * 16 + (threadIdx.x >> 4);
    int lane = threadIdx.x & 15;
    const uint2* uf = (const uint2*)u;          // row = 16 uint2
    uint2 self = uf[node * 16 + lane];
    f16x2 a0 = u2h(self.x), a1 = u2h(self.y);
    f16x2 b0 = {(_Float16)0.f, (_Float16)0.f}, b1 = b0;
    f16x2 c0 = b0, c1 = b0, d0 = b0, d1 = b0;
    int n = cnti[node];
    const int* ci = colidx + rowptr[node];
    int j = 0;
    for (; j + 4 <= n; j += 4) {
        uint2 va = uf[ci[j] * 16 + lane];
        uint2 vb = uf[ci[j + 1] * 16 + lane];
        uint2 vc = uf[ci[j + 2] * 16 + lane];
        uint2 vd = uf[ci[j + 3] * 16 + lane];
        a0 += u2h(va.x); a1 += u2h(va.y);
        b0 += u2h(vb.x); b1 += u2h(vb.y);
        c0 += u2h(vc.x); c1 += u2h(vc.y);
        d0 += u2h(vd.x); d1 += u2h(vd.y);
    }
    for (; j < n; ++j) {
        uint2 va = uf[ci[j] * 16 + lane];
        a0 += u2h(va.x); a1 += u2h(va.y);
    }
    a0 += b0 + c0 + d0;
    a1 += b1 + c1 + d1;
    float d = dinv[node];
    uint2 o;
    o.x = cvt_pkrtz_u((float)a0[0] * d, (float)a0[1] * d);
    o.y = cvt_pkrtz_u((float)a1[0] * d, (float)a1[1] * d);
    *(uint2*)&s1[node * 32 + lane * 2] = o;
}

// ---- gather2: s2 = bf16(16*dinv_n * sum fp8rows), 128ch fp8 ----
// 16 lanes/node, uint2 (8ch) per lane, 4-deep unroll, sign-free packed decode
__global__ __launch_bounds__(256) void k_gather2(const int* __restrict__ rowptr,
        const int* __restrict__ cnti, const int* __restrict__ colidx,
        const unsigned* __restrict__ u, const float* __restrict__ dinv,
        unsigned* __restrict__ s2) {
    int node = blockIdx.x * 16 + (threadIdx.x >> 4);
    int lane = threadIdx.x & 15;
    const uint2* uf = (const uint2*)u;          // row = 16 uint2 (128 fp8)
    uint2 self = uf[node * 16 + lane];
    f16x2 xa = u2h((self.x & 0x007f007fu) << 7);   // c0,c2
    f16x2 xb = u2h((self.x & 0x7f007f00u) >> 1);   // c1,c3
    f16x2 ya = u2h((self.y & 0x007f007fu) << 7);   // c4,c6
    f16x2 yb = u2h((self.y & 0x7f007f00u) >> 1);   // c5,c7
    f16x2 z = {(_Float16)0.f, (_Float16)0.f};
    f16x2 xa2 = z, xb2 = z, ya2 = z, yb2 = z;
    int n = cnti[node];
    const int* ci = colidx + rowptr[node];
    int j = 0;
    for (; j + 4 <= n; j += 4) {
        uint2 va = uf[ci[j] * 16 + lane];
        uint2 vb = uf[ci[j + 1] * 16 + lane];
        uint2 vc = uf[ci[j + 2] * 16 + lane];
        uint2 vd = uf[ci[j + 3] * 16 + lane];
        xa  += u2h((va.x & 0x007f007fu) << 7);  xb  += u2h((va.x & 0x7f007f00u) >> 1);
        ya  += u2h((va.y & 0x007f007fu) << 7);  yb  += u2h((va.y & 0x7f007f00u) >> 1);
        xa2 += u2h((vb.x & 0x007f007fu) << 7);  xb2 += u2h((vb.x & 0x7f007f00u) >> 1);
        ya2 += u2h((vb.y & 0x007f007fu) << 7);  yb2 += u2h((vb.y & 0x7f007f00u) >> 1);
        xa  += u2h((vc.x & 0x007f007fu) << 7);  xb  += u2h((vc.x & 0x7f007f00u) >> 1);
        ya  += u2h((vc.y & 0x007f007fu) << 7);  yb  += u2h((vc.y & 0x7f007f00u) >> 1);
        xa2 += u2h((vd.x & 0x007f007fu) << 7);  xb2 += u2h((vd.x & 0x7f007f00u) >> 1);
        ya2 += u2h((vd.y & 0x007f007fu) << 7);  yb2 += u2h((vd.y & 0x7f007f00u) >> 1);
    }
    for (; j < n; ++j) {
        uint2 va = uf[ci[j] * 16 + lane];
        xa += u2h((va.x & 0x007f007fu) << 7);  xb += u2h((va.x & 0x7f007f00u) >> 1);
        ya += u2h((va.y & 0x007f007fu) << 7);  yb += u2h((va.y & 0x7f007f00u) >> 1);
    }
    xa += xa2; xb += xb2; ya += ya2; yb += yb2;
    float d = dinv[node] * 16.0f;   // *256 (decode) / 16 (encode scale)
    uint4 o;
    o.x = pack_bf16x2((float)xa[0] * d, (float)xb[0] * d);   // c0,c1
    o.y = pack_bf16x2((float)xa[1] * d, (float)xb[1] * d);   // c2,c3
    o.z = pack_bf16x2((float)ya[0] * d, (float)yb[0] * d);   // c4,c5
    o.w = pack_bf16x2((float)ya[1] * d, (float)yb[1] * d);   // c6,c7
    *(uint4*)&s2[node * 64 + lane * 4] = o;
}

// ---- MFMA GEMM: h = relu(A@W + bias); AF16: f16 inputs; EPI 0: out fp8(16*dinv*h); 1: bf16 ----
template<int K, int EPI, int AF16>
__global__ __launch_bounds__(256) void k_gemm_mfma(const unsigned short* __restrict__ Ab,
        const unsigned short* __restrict__ wt, const float* __restrict__ dinv,
        const float* __restrict__ bias, void* __restrict__ outp) {
    constexpr int KS = K / 32;
    constexpr int SLOTS = K / 8;
    __shared__ __align__(16) unsigned short wlds[128 * K];
    char* lb = (char*)wlds;
    for (int c = threadIdx.x; c < 128 * SLOTS; c += 256) {
        int n = c / SLOTS, s = c - n * SLOTS;
        *(uint4*)(lb + n * (2 * K) + ((s ^ (n & 7)) << 4)) = *(const uint4*)(wt + c * 8);
    }
    __syncthreads();
    int lane = threadIdx.x & 63;
    int w = threadIdx.x >> 6;
    int r0 = blockIdx.x * 64 + w * 16;
    int arow = r0 + (lane & 15);
    if (arow >= NN) arow = NN - 1;
    bf16x8 af[KS];
    #pragma unroll
    for (int ks = 0; ks < KS; ++ks)
        af[ks] = *(const bf16x8*)&Ab[(long)arow * K + ks * 32 + (lane >> 4) * 8];
    f32x4 acc[8];
    #pragma unroll
    for (int t = 0; t < 8; ++t) acc[t] = (f32x4){0.f, 0.f, 0.f, 0.f};
    #pragma unroll
    for (int ks = 0; ks < KS; ++ks) {
        #pragma unroll
        for (int t = 0; t < 8; ++t) {
            int n = t * 16 + (lane & 15);
            int slot = ks * 4 + (lane >> 4);
            bf16x8 braw = *(const bf16x8*)(lb + n * (2 * K) + ((slot ^ (n & 7)) << 4));
            if constexpr (AF16) {
                union { bf16x8 r; f16x8 h; } ca, cb;
                ca.r = af[ks]; cb.r = braw;
                acc[t] = __builtin_amdgcn_mfma_f32_16x16x32_f16(ca.h, cb.h, acc[t], 0, 0, 0);
            } else {
                acc[t] = __builtin_amdgcn_mfma_f32_16x16x32_bf16(af[ks], braw, acc[t], 0, 0, 0);
            }
        }
    }
    float bv[8];
    #pragma unroll
    for (int t = 0; t < 8; ++t) bv[t] = bias[t * 16 + (lane & 15)];
    #pragma unroll
    for (int r = 0; r < 4; ++r) {
        long row = r0 + (lane >> 4) * 4 + r;
        if (row >= NN) continue;
        float d = dinv[row];
        #pragma unroll
        for (int t = 0; t < 8; ++t) {
            float val = fmaxf(acc[t][r] + bv[t], 0.f);
            int col = t * 16 + (lane & 15);
            if (EPI == 0)
                ((unsigned char*)outp)[row * 128 + col] = (unsigned char)f2fp8(val * (16.0f * d));
            else
                ((unsigned short*)outp)[row * 128 + col] = f2bf(val);
        }
    }
}

// ---- segmented mean pool over bf16 h2: 4 waves per graph ----
__global__ __launch_bounds__(256) void k_poolmean(const unsigned* __restrict__ h,
        const int* __restrict__ seg_end, float* __restrict__ hg) {
    __shared__ float part[3][128];
    int g = blockIdx.x;
    int w = threadIdx.x >> 6, t = threadIdx.x & 63;
    int s = (g == 0) ? 0 : seg_end[g - 1];
    int e = seg_end[g];
    float a0 = 0.f, a1 = 0.f;
    for (int i = s + w; i < e; i += 4) {
        unsigned u = h[(long)i * 64 + t];
        a0 += __uint_as_float(u << 16);
        a1 += __uint_as_float(u & 0xffff0000u);
    }
    if (w) { part[w - 1][t * 2] = a0; part[w - 1][t * 2 + 1] = a1; }
    __syncthreads();
    if (w == 0) {
        a0 += part[0][t * 2] + part[1][t * 2] + part[2][t * 2];
        a1 += part[0][t * 2 + 1] + part[1][t * 2 + 1] + part[2][t * 2 + 1];
        float inv = (e > s) ? 1.0f / (float)(e - s) : 0.f;
        float2 o = { a0 * inv, a1 * inv };
        *(float2*)&hg[g * 128 + t * 2] = o;
    }
}

// ---- mu/logvar heads + reparameterise ----
__global__ __launch_bounds__(64) void k_head(const float* __restrict__ hg,
        const float* __restrict__ Wmu, const float* __restrict__ bmu,
        const float* __restrict__ Wlv, const float* __restrict__ blv,
        const float* __restrict__ eps, float* __restrict__ mu_o, float* __restrict__ lv_o,
        float* __restrict__ z) {
    __shared__ float row[128];
    int g = blockIdx.x, t = threadIdx.x;
    row[t]      = hg[g * 128 + t];
    row[t + 64] = hg[g * 128 + t + 64];
    __syncthreads();
    float mu = bmu[t], lv = blv[t];
    for (int k = 0; k < 128; ++k) {
        float rv = row[k];
        mu += rv * Wmu[k * 64 + t];
        lv += rv * Wlv[k * 64 + t];
    }
    mu_o[g * 64 + t] = mu;
    lv_o[g * 64 + t] = lv;
    z[g * 64 + t] = mu + eps[g * 64 + t] * expf(0.5f * lv);
}

// ---- small MLP layer ----
__global__ __launch_bounds__(128) void k_mlp(const float* __restrict__ A, int K,
        const float* __restrict__ W, const float* __restrict__ b, float* __restrict__ out) {
    __shared__ float row[128];
    int m = blockIdx.x, t = threadIdx.x;
    if (t < K) row[t] = A[m * K + t];
    __syncthreads();
    float acc = b[t];
    for (int k = 0; k < K; ++k) acc += row[k] * W[k * 128 + t];
    out[m * 128 + t] = fmaxf(acc, 0.f);
}

// ---- probs = sigmoid(A @ D3_bf16 + d3); 16-row m-tiles, packed bf16 W decode ----
__global__ __launch_bounds__(256) void k_dec3(const float* __restrict__ A,
        const unsigned short* __restrict__ Wb, const float* __restrict__ b, float* __restrict__ out) {
    __shared__ float alds[16][128];
    int m0 = blockIdx.y * 16;
    for (int i = threadIdx.x; i < 16 * 128; i += 256)
        alds[i >> 7][i & 127] = A[(m0 + (i >> 7)) * 128 + (i & 127)];
    __syncthreads();
    if (threadIdx.x >= 254) return;
    int c = blockIdx.x * 1016 + threadIdx.x * 4;
    float4 bb = *(const float4*)&b[c];
    float4 acc[16];
    #pragma unroll
    for (int r = 0; r < 16; ++r) acc[r] = bb;
    for (int k = 0; k < 128; ++k) {
        uint2 u = *(const uint2*)&Wb[(long)k * OUTS + c];
        float w0 = __uint_as_float(u.x << 16);
        float w1 = __uint_as_float(u.x & 0xffff0000u);
        float w2 = __uint_as_float(u.y << 16);
        float w3 = __uint_as_float(u.y & 0xffff0000u);
        #pragma unroll
        for (int r = 0; r < 16; ++r) {
            float a = alds[r][k];
            acc[r].x += a * w0; acc[r].y += a * w1;
            acc[r].z += a * w2; acc[r].w += a * w3;
        }
    }
    #pragma unroll
    for (int r = 0; r < 16; ++r) {
        float4 o;
        o.x = 1.f / (1.f + expf(-acc[r].x));
        o.y = 1.f / (1.f + expf(-acc[r].y));
        o.z = 1.f / (1.f + expf(-acc[r].z));
        o.w = 1.f / (1.f + expf(-acc[r].w));
        *(float4*)&out[(long)(m0 + r) * OUTS + c] = o;
    }
}

// ---- build symmetric adjacency ----
__global__ __launch_bounds__(256) void k_adj(const float* __restrict__ probs, float* __restrict__ adj) {
    int t = blockIdx.x * 256 + threadIdx.x;
    int g = t >> 12;
    int rem = t & 4095;
    int r = rem >> 5;
    int c0 = (rem & 31) * 4;
    const float* pg = &probs[g * OUTS];
    float4 o;
    float* op = (float*)&o;
    #pragma unroll
    for (int j = 0; j < 4; ++j) {
        int c = c0 + j;
        if (c == r) { op[j] = 0.f; continue; }
        int a = c < r ? c : r;
        int b = c < r ? r : c;
        int k = a * (255 - a) / 2 + (b - a - 1);
        op[j] = pg[k];
    }
    *(float4*)&adj[(long)t * 4] = o;
}

extern "C" void kernel_launch(void* const* d_in, const int* in_sizes, int n_in,
                              void* d_out, int out_size, void* d_ws, size_t ws_size,
                              hipStream_t stream) {
    const float* x   = (const float*)d_in[0];
    const int*   ei  = (const int*)d_in[1];
    const int* batch = (const int*)d_in[2];
    const float* eps = (const float*)d_in[3];
    const float* W1  = (const float*)d_in[4];
    const float* b1  = (const float*)d_in[5];
    const float* W2  = (const float*)d_in[6];
    const float* b2  = (const float*)d_in[7];
    const float* Wmu = (const float*)d_in[8];
    const float* bmu = (const float*)d_in[9];
    const float* Wlv = (const float*)d_in[10];
    const float* blv = (const float*)d_in[11];
    const float* D1  = (const float*)d_in[12];
    const float* d1  = (const float*)d_in[13];
    const float* D2  = (const float*)d_in[14];
    const float* d2  = (const float*)d_in[15];
    const float* D3  = (const float*)d_in[16];
    const float* d3  = (const float*)d_in[17];

    const int* esrc = ei;
    const int* edst = ei + NE;

    float* out  = (float*)d_out;
    float* mu_o = out + 8388608;
    float* lv_o = mu_o + 32768;

    // --- CSR + small scratch in d_out (region fully overwritten by k_adj at the end) ---
    int*   colidx   = (int*)out;                  // 1,600,000
    int*   cnti     = colidx + 1600000;           // 100,000
    int*   rowptr   = cnti + 100000;              // 100,000
    int*   seg_end  = rowptr + 100000;            // 512
    float* dinv     = (float*)(seg_end + 512);    // 100,000
    int*   scanhist = (int*)(dinv + 100000);      // 196*197 = 38,612
    int*   bucketbase = scanhist + 38612;         // 196
    unsigned short* wt3 = (unsigned short*)(bucketbase + 256);  // 1,040,384 u16 (ends ~2.46M floats << 8.39M)

    // --- ws layout (float-unit offsets) ---
    float* ws = (float*)d_ws;
    unsigned* u1u = (unsigned*)ws;                         // 3.2M uints (f16x2)
    unsigned* s1u = u1u + 3200000;                         // 3.2M uints (f16x2)
    unsigned char* u2b = (unsigned char*)(ws + 6400000);   // 12.8M bytes (fp8)
    unsigned* s2u = (unsigned*)(ws + 9600000);             // 6.4M uints (bf16x2)
    unsigned* h2b = (unsigned*)(ws + 16000000);            // 6.4M uints (bf16x2)
    unsigned short* wt1 = (unsigned short*)(ws + 22400000);   // 8192 u16 (f16)
    unsigned short* wt2 = wt1 + 8192;                         // 16384 u16 (bf16)
    int* tmp = (int*)(ws + 22420000);                      // 1.6M+ ints
    // decoder scratch aliases u1/s1 (dead after gemm1)
    float* hg    = ws;
    float* zbuf  = hg + 65536;
    float* p1    = zbuf + 32768;
    float* p2    = p1 + 65536;
    float* probs = p2 + 65536;

    // ---- CSR build: zero global atomics ----
    k_part<<<NPB, 512, 0, stream>>>(esrc, edst, tmp, scanhist);
    k_btot<<<1, 256, 0, stream>>>(scanhist, bucketbase);
    k_fill2<<<NB2, 1024, 0, stream>>>(bucketbase, scanhist, tmp, colidx, cnti, rowptr, dinv);
    k_segend<<<(NN + 255) / 256, 256, 0, stream>>>(batch, seg_end);

    // ---- weights: wt1 f16, wt2 bf16 (transposed), D3 bf16 ----
    k_wt<64, 1><<<32, 256, 0, stream>>>(W1, wt1);
    k_wt<128, 0><<<64, 256, 0, stream>>>(W2, wt2);
    k_wt3<<<(128 * OUTS + 255) / 256, 256, 0, stream>>>(D3, wt3);

    // ---- conv1 (f16 gather in 64-ch x-space, then f16 MFMA GEMM -> fp8) ----
    k_scale_x<<<12500, 256, 0, stream>>>(x, dinv, u1u);
    k_gather1<<<6250, 256, 0, stream>>>(rowptr, cnti, colidx, u1u, dinv, s1u);
    k_gemm_mfma<64, 0, 1><<<1563, 256, 0, stream>>>((const unsigned short*)s1u, wt1, dinv, b1, u2b);

    // ---- conv2 (fp8 packed-decode gather, then bf16 MFMA GEMM) ----
    k_gather2<<<6250, 256, 0, stream>>>(rowptr, cnti, colidx, (const unsigned*)u2b, dinv, s2u);
    k_gemm_mfma<128, 1, 0><<<1563, 256, 0, stream>>>((const unsigned short*)s2u, wt2, dinv, b2, h2b);

    // ---- pool + heads ----
    k_poolmean<<<NG, 256, 0, stream>>>(h2b, seg_end, hg);
    k_head<<<NG, 64, 0, stream>>>(hg, Wmu, bmu, Wlv, blv, eps, mu_o, lv_o, zbuf);

    // ---- decoder ----
    k_mlp<<<NG, 128, 0, stream>>>(zbuf, 64, D1, d1, p1);
    k_mlp<<<NG, 128, 0, stream>>>(p1, 128, D2, d2, p2);
    dim3 g3(8, 32);
    k_dec3<<<g3, 256, 0, stream>>>(p2, wt3, d3, probs);
    k_adj<<<8192, 256, 0, stream>>>(probs, out);
}

// Round 12
// 240.564 us; speedup vs baseline: 1.3363x; 1.0751x over previous
//
#include <hip/hip_runtime.h>
#include <hip/hip_fp16.h>

#define NN 100000
#define NE 1600000
#define NG 512
#define OUTS 8128
#define NB2 196     // coarse buckets of 512 nodes (196*512 = 100352 >= NN)
#define CHUNK 8192
#define NPB 196     // ceil(NE/CHUNK)

typedef short bf16x8 __attribute__((ext_vector_type(8)));
typedef _Float16 f16x8 __attribute__((ext_vector_type(8)));
typedef _Float16 f16x2 __attribute__((ext_vector_type(2)));
typedef float f32x4 __attribute__((ext_vector_type(4)));

__device__ __forceinline__ unsigned pack_bf16x2(float a, float b) {
    unsigned ua = __float_as_uint(a);
    unsigned ub = __float_as_uint(b);
    ua = (ua + 0x7fffu + ((ua >> 16) & 1u)) >> 16;
    ub = (ub + 0x7fffu + ((ub >> 16) & 1u)) >> 16;
    return ua | (ub << 16);
}
__device__ __forceinline__ unsigned short f2bf(float f) {
    unsigned u = __float_as_uint(f);
    u = (u + 0x7fffu + ((u >> 16) & 1u)) >> 16;
    return (unsigned short)u;
}
// f32 pair -> packed f16x2 (RTZ), as raw uint
__device__ __forceinline__ unsigned cvt_pkrtz_u(float a, float b) {
    auto h = __builtin_amdgcn_cvt_pkrtz(a, b);
    union { decltype(h) h2; unsigned u; } c; c.h2 = h; return c.u;
}
__device__ __forceinline__ f16x2 u2h(unsigned u) { union { unsigned u; f16x2 h; } c; c.u = u; return c.h; }

// e4m3 encode for f >= 0 (relu'd): e4m3(v) == f16(v/256) with 10->3 mantissa round
__device__ __forceinline__ unsigned f2fp8(float f) {
    unsigned h = (unsigned)__half_as_ushort(__float2half(f * 0.00390625f));
    return (h + 0x3Fu + ((h >> 7) & 1u)) >> 7;
}

// ---- phase 1: partition an 8192-edge chunk into 196 coarse buckets (512 threads) ----
__global__ __launch_bounds__(512) void k_part(const int* __restrict__ src, const int* __restrict__ dst,
        int* __restrict__ tmp, int* __restrict__ scanhist) {
    __shared__ int hist[NB2], cur[NB2], scan[256];
    int p = blockIdx.x, t = threadIdx.x;
    int e0 = p * CHUNK;
    int e1 = min(e0 + CHUNK, NE);
    for (int i = t; i < NB2; i += 512) hist[i] = 0;
    __syncthreads();
    for (int e = e0 + t; e < e1; e += 512)
        atomicAdd(&hist[dst[e] >> 9], 1);
    __syncthreads();
    int h = 0;
    if (t < 256) { h = (t < NB2) ? hist[t] : 0; scan[t] = h; }
    __syncthreads();
    for (int off = 1; off < 256; off <<= 1) {
        int v = (t < 256 && t >= off) ? scan[t - off] : 0;
        __syncthreads();
        if (t < 256) scan[t] += v;
        __syncthreads();
    }
    if (t < NB2) {
        int excl = scan[t] - h;
        cur[t] = excl;
        scanhist[p * (NB2 + 1) + t] = excl;
    }
    if (t == 0) scanhist[p * (NB2 + 1) + NB2] = e1 - e0;
    __syncthreads();
    for (int e = e0 + t; e < e1; e += 512) {
        int d = dst[e];
        int b = d >> 9;
        int r = atomicAdd(&cur[b], 1);          // LDS atomic only
        tmp[e0 + r] = (src[e] << 9) | (d & 511);
    }
}

// ---- block 0: bucket totals + scan -> bucketbase; blocks 1..: segment ends ----
__global__ __launch_bounds__(256) void k_btotseg(const int* __restrict__ scanhist,
        int* __restrict__ bucketbase, const int* __restrict__ batch, int* __restrict__ seg_end) {
    if (blockIdx.x == 0) {
        __shared__ int sc[256];
        int b = threadIdx.x;
        int tot = 0;
        if (b < NB2) {
            for (int p = 0; p < NPB; ++p)
                tot += scanhist[p * (NB2 + 1) + b + 1] - scanhist[p * (NB2 + 1) + b];
        }
        sc[b] = tot;
        __syncthreads();
        for (int off = 1; off < 256; off <<= 1) {
            int v = (b >= off) ? sc[b - off] : 0;
            __syncthreads();
            sc[b] += v;
            __syncthreads();
        }
        if (b < NB2) bucketbase[b] = sc[b] - tot;
    } else {
        int i = (blockIdx.x - 1) * 256 + threadIdx.x;
        if (i >= NN) return;
        int b = batch[i];
        int bn = (i == NN - 1) ? NG : batch[i + 1];
        for (int g = b; g < bn; ++g) seg_end[g] = i + 1;
        if (i == 0) {
            for (int g = 0; g < b; ++g) seg_end[g] = 0;
        }
    }
}

// ---- phase 2: per-bucket count + scan + place (1024 threads, 16 waves) ----
__global__ __launch_bounds__(1024) void k_fill2(const int* __restrict__ bucketbase,
        const int* __restrict__ scanhist, const int* __restrict__ tmp,
        int* __restrict__ colidx, int* __restrict__ cnti, int* __restrict__ rowptr,
        float* __restrict__ dinv) {
    __shared__ int lc[512], rb[512], sc[256];
    int b = blockIdx.x, t = threadIdx.x;
    int n0 = b << 9;
    if (t < 512) lc[t] = 0;
    __syncthreads();
    int w = t >> 6, lane = t & 63;              // w in 0..15
    // count phase
    for (int p = w; p < NPB; p += 16) {
        int s0 = scanhist[p * (NB2 + 1) + b];
        int s1 = scanhist[p * (NB2 + 1) + b + 1];
        int base = p * CHUNK;
        for (int i = s0 + lane; i < s1; i += 64)
            atomicAdd(&lc[tmp[base + i] & 511], 1);
    }
    __syncthreads();
    // scan 512 via 256 pair-partials
    int v0 = 0, v1 = 0, s = 0;
    if (t < 256) { v0 = lc[2 * t]; v1 = lc[2 * t + 1]; s = v0 + v1; sc[t] = s; }
    __syncthreads();
    for (int off = 1; off < 256; off <<= 1) {
        int x = (t < 256 && t >= off) ? sc[t - off] : 0;
        __syncthreads();
        if (t < 256) sc[t] += x;
        __syncthreads();
    }
    if (t < 256) {
        int excl = sc[t] - s;
        int base0 = bucketbase[b];
        rb[2 * t] = base0 + excl;
        rb[2 * t + 1] = base0 + excl + v0;
        int node0 = n0 + 2 * t;
        if (node0 < NN) {
            cnti[node0] = v0;
            rowptr[node0] = base0 + excl;
            dinv[node0] = rsqrtf((float)v0 + 1.0f);
        }
        if (node0 + 1 < NN) {
            cnti[node0 + 1] = v1;
            rowptr[node0 + 1] = base0 + excl + v0;
            dinv[node0 + 1] = rsqrtf((float)v1 + 1.0f);
        }
    }
    __syncthreads();
    if (t < 512) lc[t] = 0;
    __syncthreads();
    // place phase
    for (int p = w; p < NPB; p += 16) {
        int s0 = scanhist[p * (NB2 + 1) + b];
        int s1 = scanhist[p * (NB2 + 1) + b + 1];
        int base = p * CHUNK;
        for (int i = s0 + lane; i < s1; i += 64) {
            int v = tmp[base + i];
            int dl = v & 511;
            int pos = atomicAdd(&lc[dl], 1);    // LDS atomic only
            colidx[rb[dl] + pos] = v >> 9;
        }
    }
}

// ---- all weight conversions in one kernel ----
__global__ __launch_bounds__(256) void k_wtall(const float* __restrict__ W1,
        const float* __restrict__ W2, const float* __restrict__ D3,
        unsigned short* __restrict__ wt1, unsigned short* __restrict__ wt2,
        unsigned short* __restrict__ wt3) {
    int i = blockIdx.x * 256 + threadIdx.x;
    if (i < 8192) {                              // wt1: [128][64] f16, transposed
        int n = i >> 6, k = i & 63;
        wt1[i] = (unsigned short)__half_as_ushort(__float2half(W1[k * 128 + n]));
    } else if (i < 24576) {                      // wt2: [128][128] bf16, transposed
        int e = i - 8192;
        int n = e >> 7, k = e & 127;
        wt2[e] = f2bf(W2[k * 128 + n]);
    } else {                                     // wt3: D3 bf16, same layout
        int e = i - 24576;
        if (e < 128 * OUTS) wt3[e] = f2bf(D3[e]);
    }
}

// ---- u1 = f16(x * dinv[row]), 64ch ----
__global__ __launch_bounds__(256) void k_scale_x(const float* __restrict__ x,
        const float* __restrict__ dinv, unsigned* __restrict__ u1) {
    int i = blockIdx.x * 256 + threadIdx.x;   // < NN*32
    int row = i >> 5, c = i & 31;
    float2 v = *(const float2*)&x[(long)row * 64 + c * 2];
    float d = dinv[row];
    u1[i] = cvt_pkrtz_u(v.x * d, v.y * d);
}

// ---- gather1: s1 = f16(dinv_n * (u1[n] + sum u1[src])), 64ch f16 ----
// 8 lanes/node, uint4 (8ch) per lane, 4-deep neighbor unroll (64B in flight/lane)
__global__ __launch_bounds__(256) void k_gather1(const int* __restrict__ rowptr,
        const int* __restrict__ cnti, const int* __restrict__ colidx,
        const unsigned* __restrict__ u, const float* __restrict__ dinv,
        unsigned* __restrict__ s1) {
    int node = blockIdx.x * 32 + (threadIdx.x >> 3);
    int lane = threadIdx.x & 7;
    const uint4* uf = (const uint4*)u;          // row = 8 uint4
    uint4 self = uf[node * 8 + lane];
    f16x2 a0 = u2h(self.x), a1 = u2h(self.y), a2 = u2h(self.z), a3 = u2h(self.w);
    f16x2 z = {(_Float16)0.f, (_Float16)0.f};
    f16x2 b0 = z, b1 = z, b2 = z, b3 = z;
    int n = cnti[node];
    const int* ci = colidx + rowptr[node];
    int j = 0;
    for (; j + 4 <= n; j += 4) {
        uint4 va = uf[ci[j] * 8 + lane];
        uint4 vb = uf[ci[j + 1] * 8 + lane];
        uint4 vc = uf[ci[j + 2] * 8 + lane];
        uint4 vd = uf[ci[j + 3] * 8 + lane];
        a0 += u2h(va.x); a1 += u2h(va.y); a2 += u2h(va.z); a3 += u2h(va.w);
        b0 += u2h(vb.x); b1 += u2h(vb.y); b2 += u2h(vb.z); b3 += u2h(vb.w);
        a0 += u2h(vc.x); a1 += u2h(vc.y); a2 += u2h(vc.z); a3 += u2h(vc.w);
        b0 += u2h(vd.x); b1 += u2h(vd.y); b2 += u2h(vd.z); b3 += u2h(vd.w);
    }
    for (; j < n; ++j) {
        uint4 va = uf[ci[j] * 8 + lane];
        a0 += u2h(va.x); a1 += u2h(va.y); a2 += u2h(va.z); a3 += u2h(va.w);
    }
    a0 += b0; a1 += b1; a2 += b2; a3 += b3;
    float d = dinv[node];
    uint4 o;
    o.x = cvt_pkrtz_u((float)a0[0] * d, (float)a0[1] * d);
    o.y = cvt_pkrtz_u((float)a1[0] * d, (float)a1[1] * d);
    o.z = cvt_pkrtz_u((float)a2[0] * d, (float)a2[1] * d);
    o.w = cvt_pkrtz_u((float)a3[0] * d, (float)a3[1] * d);
    *(uint4*)&s1[node * 32 + lane * 4] = o;
}

// ---- gather2: s2 = bf16(16*dinv_n * sum fp8rows), 128ch fp8 ----
// 8 lanes/node, uint4 (16ch) per lane, 4-deep unroll, sign-free packed decode
#define DECO(W, LO, HI) { LO += u2h(((W) & 0x007f007fu) << 7); HI += u2h(((W) & 0x7f007f00u) >> 1); }
__global__ __launch_bounds__(256) void k_gather2(const int* __restrict__ rowptr,
        const int* __restrict__ cnti, const int* __restrict__ colidx,
        const unsigned* __restrict__ u, const float* __restrict__ dinv,
        unsigned* __restrict__ s2) {
    int node = blockIdx.x * 32 + (threadIdx.x >> 3);
    int lane = threadIdx.x & 7;
    const uint4* uf = (const uint4*)u;          // row = 8 uint4 (128 fp8)
    uint4 self = uf[node * 8 + lane];
    f16x2 z = {(_Float16)0.f, (_Float16)0.f};
    f16x2 la0 = z, ha0 = z, la1 = z, ha1 = z, la2 = z, ha2 = z, la3 = z, ha3 = z;
    f16x2 lb0 = z, hb0 = z, lb1 = z, hb1 = z, lb2 = z, hb2 = z, lb3 = z, hb3 = z;
    DECO(self.x, la0, ha0) DECO(self.y, la1, ha1) DECO(self.z, la2, ha2) DECO(self.w, la3, ha3)
    int n = cnti[node];
    const int* ci = colidx + rowptr[node];
    int j = 0;
    for (; j + 4 <= n; j += 4) {
        uint4 va = uf[ci[j] * 8 + lane];
        uint4 vb = uf[ci[j + 1] * 8 + lane];
        uint4 vc = uf[ci[j + 2] * 8 + lane];
        uint4 vd = uf[ci[j + 3] * 8 + lane];
        DECO(va.x, la0, ha0) DECO(va.y, la1, ha1) DECO(va.z, la2, ha2) DECO(va.w, la3, ha3)
        DECO(vb.x, lb0, hb0) DECO(vb.y, lb1, hb1) DECO(vb.z, lb2, hb2) DECO(vb.w, lb3, hb3)
        DECO(vc.x, la0, ha0) DECO(vc.y, la1, ha1) DECO(vc.z, la2, ha2) DECO(vc.w, la3, ha3)
        DECO(vd.x, lb0, hb0) DECO(vd.y, lb1, hb1) DECO(vd.z, lb2, hb2) DECO(vd.w, lb3, hb3)
    }
    for (; j < n; ++j) {
        uint4 va = uf[ci[j] * 8 + lane];
        DECO(va.x, la0, ha0) DECO(va.y, la1, ha1) DECO(va.z, la2, ha2) DECO(va.w, la3, ha3)
    }
    la0 += lb0; ha0 += hb0; la1 += lb1; ha1 += hb1;
    la2 += lb2; ha2 += hb2; la3 += lb3; ha3 += hb3;
    float d = dinv[node] * 16.0f;   // *256 (decode) / 16 (encode scale)
    uint4 o1, o2;
    o1.x = pack_bf16x2((float)la0[0] * d, (float)ha0[0] * d);
    o1.y = pack_bf16x2((float)la0[1] * d, (float)ha0[1] * d);
    o1.z = pack_bf16x2((float)la1[0] * d, (float)ha1[0] * d);
    o1.w = pack_bf16x2((float)la1[1] * d, (float)ha1[1] * d);
    o2.x = pack_bf16x2((float)la2[0] * d, (float)ha2[0] * d);
    o2.y = pack_bf16x2((float)la2[1] * d, (float)ha2[1] * d);
    o2.z = pack_bf16x2((float)la3[0] * d, (float)ha3[0] * d);
    o2.w = pack_bf16x2((float)la3[1] * d, (float)ha3[1] * d);
    *(uint4*)&s2[node * 64 + lane * 8] = o1;
    *(uint4*)&s2[node * 64 + lane * 8 + 4] = o2;
}

// ---- MFMA GEMM: h = relu(A@W + bias); AF16: f16 inputs; EPI 0: out fp8(16*dinv*h); 1: bf16 ----
template<int K, int EPI, int AF16>
__global__ __launch_bounds__(256) void k_gemm_mfma(const unsigned short* __restrict__ Ab,
        const unsigned short* __restrict__ wt, const float* __restrict__ dinv,
        const float* __restrict__ bias, void* __restrict__ outp) {
    constexpr int KS = K / 32;
    constexpr int SLOTS = K / 8;
    __shared__ __align__(16) unsigned short wlds[128 * K];
    char* lb = (char*)wlds;
    for (int c = threadIdx.x; c < 128 * SLOTS; c += 256) {
        int n = c / SLOTS, s = c - n * SLOTS;
        *(uint4*)(lb + n * (2 * K) + ((s ^ (n & 7)) << 4)) = *(const uint4*)(wt + c * 8);
    }
    __syncthreads();
    int lane = threadIdx.x & 63;
    int w = threadIdx.x >> 6;
    int r0 = blockIdx.x * 64 + w * 16;
    int arow = r0 + (lane & 15);
    if (arow >= NN) arow = NN - 1;
    bf16x8 af[KS];
    #pragma unroll
    for (int ks = 0; ks < KS; ++ks)
        af[ks] = *(const bf16x8*)&Ab[(long)arow * K + ks * 32 + (lane >> 4) * 8];
    f32x4 acc[8];
    #pragma unroll
    for (int t = 0; t < 8; ++t) acc[t] = (f32x4){0.f, 0.f, 0.f, 0.f};
    #pragma unroll
    for (int ks = 0; ks < KS; ++ks) {
        #pragma unroll
        for (int t = 0; t < 8; ++t) {
            int n = t * 16 + (lane & 15);
            int slot = ks * 4 + (lane >> 4);
            bf16x8 braw = *(const bf16x8*)(lb + n * (2 * K) + ((slot ^ (n & 7)) << 4));
            if constexpr (AF16) {
                union { bf16x8 r; f16x8 h; } ca, cb;
                ca.r = af[ks]; cb.r = braw;
                acc[t] = __builtin_amdgcn_mfma_f32_16x16x32_f16(ca.h, cb.h, acc[t], 0, 0, 0);
            } else {
                acc[t] = __builtin_amdgcn_mfma_f32_16x16x32_bf16(af[ks], braw, acc[t], 0, 0, 0);
            }
        }
    }
    float bv[8];
    #pragma unroll
    for (int t = 0; t < 8; ++t) bv[t] = bias[t * 16 + (lane & 15)];
    #pragma unroll
    for (int r = 0; r < 4; ++r) {
        long row = r0 + (lane >> 4) * 4 + r;
        if (row >= NN) continue;
        float d = dinv[row];
        #pragma unroll
        for (int t = 0; t < 8; ++t) {
            float val = fmaxf(acc[t][r] + bv[t], 0.f);
            int col = t * 16 + (lane & 15);
            if (EPI == 0)
                ((unsigned char*)outp)[row * 128 + col] = (unsigned char)f2fp8(val * (16.0f * d));
            else
                ((unsigned short*)outp)[row * 128 + col] = f2bf(val);
        }
    }
}

// ---- segmented mean pool over bf16 h2: 4 waves per graph ----
__global__ __launch_bounds__(256) void k_poolmean(const unsigned* __restrict__ h,
        const int* __restrict__ seg_end, float* __restrict__ hg) {
    __shared__ float part[3][128];
    int g = blockIdx.x;
    int w = threadIdx.x >> 6, t = threadIdx.x & 63;
    int s = (g == 0) ? 0 : seg_end[g - 1];
    int e = seg_end[g];
    float a0 = 0.f, a1 = 0.f;
    for (int i = s + w; i < e; i += 4) {
        unsigned u = h[(long)i * 64 + t];
        a0 += __uint_as_float(u << 16);
        a1 += __uint_as_float(u & 0xffff0000u);
    }
    if (w) { part[w - 1][t * 2] = a0; part[w - 1][t * 2 + 1] = a1; }
    __syncthreads();
    if (w == 0) {
        a0 += part[0][t * 2] + part[1][t * 2] + part[2][t * 2];
        a1 += part[0][t * 2 + 1] + part[1][t * 2 + 1] + part[2][t * 2 + 1];
        float inv = (e > s) ? 1.0f / (float)(e - s) : 0.f;
        float2 o = { a0 * inv, a1 * inv };
        *(float2*)&hg[g * 128 + t * 2] = o;
    }
}

// ---- fused decoder head: mu/lv/z + 2 MLP layers; one block (128 thr) per graph ----
__global__ __launch_bounds__(128) void k_decfused(const float* __restrict__ hg,
        const float* __restrict__ Wmu, const float* __restrict__ bmu,
        const float* __restrict__ Wlv, const float* __restrict__ blv,
        const float* __restrict__ eps,
        const float* __restrict__ D1, const float* __restrict__ d1,
        const float* __restrict__ D2, const float* __restrict__ d2,
        float* __restrict__ mu_o, float* __restrict__ lv_o, float* __restrict__ p2out) {
    __shared__ float row[128], mlv[128], zr[64], p1[128];
    int g = blockIdx.x, t = threadIdx.x;
    row[t] = hg[g * 128 + t];
    __syncthreads();
    if (t < 64) {
        float acc = bmu[t];
        for (int k = 0; k < 128; ++k) acc += row[k] * Wmu[k * 64 + t];
        mlv[t] = acc;
    } else {
        int t2 = t - 64;
        float acc = blv[t2];
        for (int k = 0; k < 128; ++k) acc += row[k] * Wlv[k * 64 + t2];
        mlv[64 + t2] = acc;
    }
    __syncthreads();
    if (t < 64) {
        float mu = mlv[t], lv = mlv[64 + t];
        mu_o[g * 64 + t] = mu;
        lv_o[g * 64 + t] = lv;
        zr[t] = mu + eps[g * 64 + t] * expf(0.5f * lv);
    }
    __syncthreads();
    float acc = d1[t];
    for (int k = 0; k < 64; ++k) acc += zr[k] * D1[k * 128 + t];
    p1[t] = fmaxf(acc, 0.f);
    __syncthreads();
    acc = d2[t];
    for (int k = 0; k < 128; ++k) acc += p1[k] * D2[k * 128 + t];
    p2out[g * 128 + t] = fmaxf(acc, 0.f);
}

// ---- probs = sigmoid(A @ D3_bf16 + d3); 16-row m-tiles, packed bf16 W decode ----
__global__ __launch_bounds__(256) void k_dec3(const float* __restrict__ A,
        const unsigned short* __restrict__ Wb, const float* __restrict__ b, float* __restrict__ out) {
    __shared__ float alds[16][128];
    int m0 = blockIdx.y * 16;
    for (int i = threadIdx.x; i < 16 * 128; i += 256)
        alds[i >> 7][i & 127] = A[(m0 + (i >> 7)) * 128 + (i & 127)];
    __syncthreads();
    if (threadIdx.x >= 254) return;
    int c = blockIdx.x * 1016 + threadIdx.x * 4;
    float4 bb = *(const float4*)&b[c];
    float4 acc[16];
    #pragma unroll
    for (int r = 0; r < 16; ++r) acc[r] = bb;
    for (int k = 0; k < 128; ++k) {
        uint2 u = *(const uint2*)&Wb[(long)k * OUTS + c];
        float w0 = __uint_as_float(u.x << 16);
        float w1 = __uint_as_float(u.x & 0xffff0000u);
        float w2 = __uint_as_float(u.y << 16);
        float w3 = __uint_as_float(u.y & 0xffff0000u);
        #pragma unroll
        for (int r = 0; r < 16; ++r) {
            float a = alds[r][k];
            acc[r].x += a * w0; acc[r].y += a * w1;
            acc[r].z += a * w2; acc[r].w += a * w3;
        }
    }
    #pragma unroll
    for (int r = 0; r < 16; ++r) {
        float4 o;
        o.x = 1.f / (1.f + expf(-acc[r].x));
        o.y = 1.f / (1.f + expf(-acc[r].y));
        o.z = 1.f / (1.f + expf(-acc[r].z));
        o.w = 1.f / (1.f + expf(-acc[r].w));
        *(float4*)&out[(long)(m0 + r) * OUTS + c] = o;
    }
}

// ---- build symmetric adjacency ----
__global__ __launch_bounds__(256) void k_adj(const float* __restrict__ probs, float* __restrict__ adj) {
    int t = blockIdx.x * 256 + threadIdx.x;
    int g = t >> 12;
    int rem = t & 4095;
    int r = rem >> 5;
    int c0 = (rem & 31) * 4;
    const float* pg = &probs[g * OUTS];
    float4 o;
    float* op = (float*)&o;
    #pragma unroll
    for (int j = 0; j < 4; ++j) {
        int c = c0 + j;
        if (c == r) { op[j] = 0.f; continue; }
        int a = c < r ? c : r;
        int b = c < r ? r : c;
        int k = a * (255 - a) / 2 + (b - a - 1);
        op[j] = pg[k];
    }
    *(float4*)&adj[(long)t * 4] = o;
}

extern "C" void kernel_launch(void* const* d_in, const int* in_sizes, int n_in,
                              void* d_out, int out_size, void* d_ws, size_t ws_size,
                              hipStream_t stream) {
    const float* x   = (const float*)d_in[0];
    const int*   ei  = (const int*)d_in[1];
    const int* batch = (const int*)d_in[2];
    const float* eps = (const float*)d_in[3];
    const float* W1  = (const float*)d_in[4];
    const float* b1  = (const float*)d_in[5];
    const float* W2  = (const float*)d_in[6];
    const float* b2  = (const float*)d_in[7];
    const float* Wmu = (const float*)d_in[8];
    const float* bmu = (const float*)d_in[9];
    const float* Wlv = (const float*)d_in[10];
    const float* blv = (const float*)d_in[11];
    const float* D1  = (const float*)d_in[12];
    const float* d1  = (const float*)d_in[13];
    const float* D2  = (const float*)d_in[14];
    const float* d2  = (const float*)d_in[15];
    const float* D3  = (const float*)d_in[16];
    const float* d3  = (const float*)d_in[17];

    const int* esrc = ei;
    const int* edst = ei + NE;

    float* out  = (float*)d_out;
    float* mu_o = out + 8388608;
    float* lv_o = mu_o + 32768;

    // --- CSR + small scratch in d_out (region fully overwritten by k_adj at the end) ---
    int*   colidx   = (int*)out;                  // 1,600,000
    int*   cnti     = colidx + 1600000;           // 100,000
    int*   rowptr   = cnti + 100000;              // 100,000
    int*   seg_end  = rowptr + 100000;            // 512
    float* dinv     = (float*)(seg_end + 512);    // 100,000
    int*   scanhist = (int*)(dinv + 100000);      // 196*197 = 38,612
    int*   bucketbase = scanhist + 38612;         // 196
    unsigned short* wt3 = (unsigned short*)(bucketbase + 256);  // 1,040,384 u16 (ends ~2.46M floats << 8.39M)

    // --- ws layout (float-unit offsets) ---
    float* ws = (float*)d_ws;
    unsigned* u1u = (unsigned*)ws;                         // 3.2M uints (f16x2)
    unsigned* s1u = u1u + 3200000;                         // 3.2M uints (f16x2)
    unsigned char* u2b = (unsigned char*)(ws + 6400000);   // 12.8M bytes (fp8)
    unsigned* s2u = (unsigned*)(ws + 9600000);             // 6.4M uints (bf16x2)
    unsigned* h2b = (unsigned*)(ws + 16000000);            // 6.4M uints (bf16x2)
    unsigned short* wt1 = (unsigned short*)(ws + 22400000);   // 8192 u16 (f16)
    unsigned short* wt2 = wt1 + 8192;                         // 16384 u16 (bf16)
    int* tmp = (int*)(ws + 22420000);                      // 1.6M+ ints
    // decoder scratch aliases u1/s1 (dead after gemm1)
    float* hg    = ws;
    float* p2    = hg + 65536;
    float* probs = p2 + 65536;

    // ---- CSR build: zero global atomics ----
    k_part<<<NPB, 512, 0, stream>>>(esrc, edst, tmp, scanhist);
    k_btotseg<<<392, 256, 0, stream>>>(scanhist, bucketbase, batch, seg_end);
    k_fill2<<<NB2, 1024, 0, stream>>>(bucketbase, scanhist, tmp, colidx, cnti, rowptr, dinv);

    // ---- all weight conversions (wt1 f16, wt2 bf16, D3 bf16) ----
    k_wtall<<<4161, 256, 0, stream>>>(W1, W2, D3, wt1, wt2, wt3);

    // ---- conv1 (f16 gather in 64-ch x-space, then f16 MFMA GEMM -> fp8) ----
    k_scale_x<<<12500, 256, 0, stream>>>(x, dinv, u1u);
    k_gather1<<<3125, 256, 0, stream>>>(rowptr, cnti, colidx, u1u, dinv, s1u);
    k_gemm_mfma<64, 0, 1><<<1563, 256, 0, stream>>>((const unsigned short*)s1u, wt1, dinv, b1, u2b);

    // ---- conv2 (fp8 packed-decode gather, then bf16 MFMA GEMM) ----
    k_gather2<<<3125, 256, 0, stream>>>(rowptr, cnti, colidx, (const unsigned*)u2b, dinv, s2u);
    k_gemm_mfma<128, 1, 0><<<1563, 256, 0, stream>>>((const unsigned short*)s2u, wt2, dinv, b2, h2b);

    // ---- pool + fused decoder head ----
    k_poolmean<<<NG, 256, 0, stream>>>(h2b, seg_end, hg);
    k_decfused<<<NG, 128, 0, stream>>>(hg, Wmu, bmu, Wlv, blv, eps, D1, d1, D2, d2,
                                       mu_o, lv_o, p2);

    // ---- decoder output + adjacency ----
    dim3 g3(8, 32);
    k_dec3<<<g3, 256, 0, stream>>>(p2, wt3, d3, probs);
    k_adj<<<8192, 256, 0, stream>>>(probs, out);
}

// Round 13
// 220.599 us; speedup vs baseline: 1.4572x; 1.0905x over previous
//
#include <hip/hip_runtime.h>
#include <hip/hip_fp16.h>

#define NN 100000
#define NE 1600000
#define NG 512
#define OUTS 8128
#define NB2 196     // coarse buckets of 512 nodes (196*512 = 100352 >= NN)
#define CHUNK 8192
#define NPB 196     // ceil(NE/CHUNK)

typedef short bf16x8 __attribute__((ext_vector_type(8)));
typedef _Float16 f16x8 __attribute__((ext_vector_type(8)));
typedef _Float16 f16x2 __attribute__((ext_vector_type(2)));
typedef float f32x4 __attribute__((ext_vector_type(4)));

__device__ __forceinline__ unsigned pack_bf16x2(float a, float b) {
    unsigned ua = __float_as_uint(a);
    unsigned ub = __float_as_uint(b);
    ua = (ua + 0x7fffu + ((ua >> 16) & 1u)) >> 16;
    ub = (ub + 0x7fffu + ((ub >> 16) & 1u)) >> 16;
    return ua | (ub << 16);
}
__device__ __forceinline__ unsigned short f2bf(float f) {
    unsigned u = __float_as_uint(f);
    u = (u + 0x7fffu + ((u >> 16) & 1u)) >> 16;
    return (unsigned short)u;
}
// f32 pair -> packed f16x2 (RTZ), as raw uint
__device__ __forceinline__ unsigned cvt_pkrtz_u(float a, float b) {
    auto h = __builtin_amdgcn_cvt_pkrtz(a, b);
    union { decltype(h) h2; unsigned u; } c; c.h2 = h; return c.u;
}
__device__ __forceinline__ f16x2 u2h(unsigned u) { union { unsigned u; f16x2 h; } c; c.u = u; return c.h; }

// e4m3 encode for f >= 0 (relu'd): e4m3(v) == f16(v/256) with 10->3 mantissa round
__device__ __forceinline__ unsigned f2fp8(float f) {
    unsigned h = (unsigned)__half_as_ushort(__float2half(f * 0.00390625f));
    return (h + 0x3Fu + ((h >> 7) & 1u)) >> 7;
}

// ---- phase 1: partition an 8192-edge chunk into 196 coarse buckets (512 threads) ----
__global__ __launch_bounds__(512) void k_part(const int* __restrict__ src, const int* __restrict__ dst,
        int* __restrict__ tmp, int* __restrict__ scanhist) {
    __shared__ int hist[NB2], cur[NB2], scan[256];
    int p = blockIdx.x, t = threadIdx.x;
    int e0 = p * CHUNK;
    int e1 = min(e0 + CHUNK, NE);
    for (int i = t; i < NB2; i += 512) hist[i] = 0;
    __syncthreads();
    for (int e = e0 + t; e < e1; e += 512)
        atomicAdd(&hist[dst[e] >> 9], 1);
    __syncthreads();
    int h = 0;
    if (t < 256) { h = (t < NB2) ? hist[t] : 0; scan[t] = h; }
    __syncthreads();
    for (int off = 1; off < 256; off <<= 1) {
        int v = (t < 256 && t >= off) ? scan[t - off] : 0;
        __syncthreads();
        if (t < 256) scan[t] += v;
        __syncthreads();
    }
    if (t < NB2) {
        int excl = scan[t] - h;
        cur[t] = excl;
        scanhist[p * (NB2 + 1) + t] = excl;
    }
    if (t == 0) scanhist[p * (NB2 + 1) + NB2] = e1 - e0;
    __syncthreads();
    for (int e = e0 + t; e < e1; e += 512) {
        int d = dst[e];
        int b = d >> 9;
        int r = atomicAdd(&cur[b], 1);          // LDS atomic only
        tmp[e0 + r] = (src[e] << 9) | (d & 511);
    }
}

// ---- block 0: bucket totals + scan -> bucketbase; blocks 1..: segment ends ----
__global__ __launch_bounds__(256) void k_btotseg(const int* __restrict__ scanhist,
        int* __restrict__ bucketbase, const int* __restrict__ batch, int* __restrict__ seg_end) {
    if (blockIdx.x == 0) {
        __shared__ int sc[256];
        int b = threadIdx.x;
        int tot = 0;
        if (b < NB2) {
            for (int p = 0; p < NPB; ++p)
                tot += scanhist[p * (NB2 + 1) + b + 1] - scanhist[p * (NB2 + 1) + b];
        }
        sc[b] = tot;
        __syncthreads();
        for (int off = 1; off < 256; off <<= 1) {
            int v = (b >= off) ? sc[b - off] : 0;
            __syncthreads();
            sc[b] += v;
            __syncthreads();
        }
        if (b < NB2) bucketbase[b] = sc[b] - tot;
    } else {
        int i = (blockIdx.x - 1) * 256 + threadIdx.x;
        if (i >= NN) return;
        int b = batch[i];
        int bn = (i == NN - 1) ? NG : batch[i + 1];
        for (int g = b; g < bn; ++g) seg_end[g] = i + 1;
        if (i == 0) {
            for (int g = 0; g < b; ++g) seg_end[g] = 0;
        }
    }
}

// ---- phase 2: per-bucket count + scan + place (1024 threads, 16 waves) ----
__global__ __launch_bounds__(1024) void k_fill2(const int* __restrict__ bucketbase,
        const int* __restrict__ scanhist, const int* __restrict__ tmp,
        int* __restrict__ colidx, int* __restrict__ cnti, int* __restrict__ rowptr,
        float* __restrict__ dinv) {
    __shared__ int lc[512], rb[512], sc[256];
    int b = blockIdx.x, t = threadIdx.x;
    int n0 = b << 9;
    if (t < 512) lc[t] = 0;
    __syncthreads();
    int w = t >> 6, lane = t & 63;              // w in 0..15
    // count phase
    for (int p = w; p < NPB; p += 16) {
        int s0 = scanhist[p * (NB2 + 1) + b];
        int s1 = scanhist[p * (NB2 + 1) + b + 1];
        int base = p * CHUNK;
        for (int i = s0 + lane; i < s1; i += 64)
            atomicAdd(&lc[tmp[base + i] & 511], 1);
    }
    __syncthreads();
    // scan 512 via 256 pair-partials
    int v0 = 0, v1 = 0, s = 0;
    if (t < 256) { v0 = lc[2 * t]; v1 = lc[2 * t + 1]; s = v0 + v1; sc[t] = s; }
    __syncthreads();
    for (int off = 1; off < 256; off <<= 1) {
        int x = (t < 256 && t >= off) ? sc[t - off] : 0;
        __syncthreads();
        if (t < 256) sc[t] += x;
        __syncthreads();
    }
    if (t < 256) {
        int excl = sc[t] - s;
        int base0 = bucketbase[b];
        rb[2 * t] = base0 + excl;
        rb[2 * t + 1] = base0 + excl + v0;
        int node0 = n0 + 2 * t;
        if (node0 < NN) {
            cnti[node0] = v0;
            rowptr[node0] = base0 + excl;
            dinv[node0] = rsqrtf((float)v0 + 1.0f);
        }
        if (node0 + 1 < NN) {
            cnti[node0 + 1] = v1;
            rowptr[node0 + 1] = base0 + excl + v0;
            dinv[node0 + 1] = rsqrtf((float)v1 + 1.0f);
        }
    }
    __syncthreads();
    if (t < 512) lc[t] = 0;
    __syncthreads();
    // place phase
    for (int p = w; p < NPB; p += 16) {
        int s0 = scanhist[p * (NB2 + 1) + b];
        int s1 = scanhist[p * (NB2 + 1) + b + 1];
        int base = p * CHUNK;
        for (int i = s0 + lane; i < s1; i += 64) {
            int v = tmp[base + i];
            int dl = v & 511;
            int pos = atomicAdd(&lc[dl], 1);    // LDS atomic only
            colidx[rb[dl] + pos] = v >> 9;
        }
    }
}

// ---- conv weight conversions (wt1 f16, wt2 bf16, both transposed) ----
__global__ __launch_bounds__(256) void k_wtall(const float* __restrict__ W1,
        const float* __restrict__ W2,
        unsigned short* __restrict__ wt1, unsigned short* __restrict__ wt2) {
    int i = blockIdx.x * 256 + threadIdx.x;
    if (i < 8192) {                              // wt1: [128][64] f16, transposed
        int n = i >> 6, k = i & 63;
        wt1[i] = (unsigned short)__half_as_ushort(__float2half(W1[k * 128 + n]));
    } else if (i < 24576) {                      // wt2: [128][128] bf16, transposed
        int e = i - 8192;
        int n = e >> 7, k = e & 127;
        wt2[e] = f2bf(W2[k * 128 + n]);
    }
}

// ---- D3 [128][OUTS] f32 -> wt3t [OUTS][128] f16 (tiled transpose) ----
__global__ __launch_bounds__(256) void k_wt3t(const float* __restrict__ D3,
        unsigned short* __restrict__ o) {
    __shared__ float tile[32][33];
    int n0 = blockIdx.x * 32, k0 = blockIdx.y * 32;
    for (int i = threadIdx.x; i < 1024; i += 256) {
        int kk = i >> 5, nn = i & 31;
        tile[kk][nn] = D3[(long)(k0 + kk) * OUTS + n0 + nn];
    }
    __syncthreads();
    for (int i = threadIdx.x; i < 1024; i += 256) {
        int nn = i >> 5, kk = i & 31;
        o[(long)(n0 + nn) * 128 + k0 + kk] =
            (unsigned short)__half_as_ushort(__float2half(tile[kk][nn]));
    }
}

// ---- u1 = f16(x * dinv[row]), 64ch ----
__global__ __launch_bounds__(256) void k_scale_x(const float* __restrict__ x,
        const float* __restrict__ dinv, unsigned* __restrict__ u1) {
    int i = blockIdx.x * 256 + threadIdx.x;   // < NN*32
    int row = i >> 5, c = i & 31;
    float2 v = *(const float2*)&x[(long)row * 64 + c * 2];
    float d = dinv[row];
    u1[i] = cvt_pkrtz_u(v.x * d, v.y * d);
}

// ---- gather1: s1 = f16(dinv_n * (u1[n] + sum u1[src])), 64ch f16 ----
// 8 lanes/node, uint4 (8ch) per lane, 4-deep neighbor unroll (64B in flight/lane)
__global__ __launch_bounds__(256) void k_gather1(const int* __restrict__ rowptr,
        const int* __restrict__ cnti, const int* __restrict__ colidx,
        const unsigned* __restrict__ u, const float* __restrict__ dinv,
        unsigned* __restrict__ s1) {
    int node = blockIdx.x * 32 + (threadIdx.x >> 3);
    int lane = threadIdx.x & 7;
    const uint4* uf = (const uint4*)u;          // row = 8 uint4
    uint4 self = uf[node * 8 + lane];
    f16x2 a0 = u2h(self.x), a1 = u2h(self.y), a2 = u2h(self.z), a3 = u2h(self.w);
    f16x2 z = {(_Float16)0.f, (_Float16)0.f};
    f16x2 b0 = z, b1 = z, b2 = z, b3 = z;
    int n = cnti[node];
    const int* ci = colidx + rowptr[node];
    int j = 0;
    for (; j + 4 <= n; j += 4) {
        uint4 va = uf[ci[j] * 8 + lane];
        uint4 vb = uf[ci[j + 1] * 8 + lane];
        uint4 vc = uf[ci[j + 2] * 8 + lane];
        uint4 vd = uf[ci[j + 3] * 8 + lane];
        a0 += u2h(va.x); a1 += u2h(va.y); a2 += u2h(va.z); a3 += u2h(va.w);
        b0 += u2h(vb.x); b1 += u2h(vb.y); b2 += u2h(vb.z); b3 += u2h(vb.w);
        a0 += u2h(vc.x); a1 += u2h(vc.y); a2 += u2h(vc.z); a3 += u2h(vc.w);
        b0 += u2h(vd.x); b1 += u2h(vd.y); b2 += u2h(vd.z); b3 += u2h(vd.w);
    }
    for (; j < n; ++j) {
        uint4 va = uf[ci[j] * 8 + lane];
        a0 += u2h(va.x); a1 += u2h(va.y); a2 += u2h(va.z); a3 += u2h(va.w);
    }
    a0 += b0; a1 += b1; a2 += b2; a3 += b3;
    float d = dinv[node];
    uint4 o;
    o.x = cvt_pkrtz_u((float)a0[0] * d, (float)a0[1] * d);
    o.y = cvt_pkrtz_u((float)a1[0] * d, (float)a1[1] * d);
    o.z = cvt_pkrtz_u((float)a2[0] * d, (float)a2[1] * d);
    o.w = cvt_pkrtz_u((float)a3[0] * d, (float)a3[1] * d);
    *(uint4*)&s1[node * 32 + lane * 4] = o;
}

// ---- gather2: s2 = bf16(16*dinv_n * sum fp8rows), 128ch fp8 ----
// 8 lanes/node, uint4 (16ch) per lane, 4-deep unroll, sign-free packed decode
#define DECO(W, LO, HI) { LO += u2h(((W) & 0x007f007fu) << 7); HI += u2h(((W) & 0x7f007f00u) >> 1); }
__global__ __launch_bounds__(256) void k_gather2(const int* __restrict__ rowptr,
        const int* __restrict__ cnti, const int* __restrict__ colidx,
        const unsigned* __restrict__ u, const float* __restrict__ dinv,
        unsigned* __restrict__ s2) {
    int node = blockIdx.x * 32 + (threadIdx.x >> 3);
    int lane = threadIdx.x & 7;
    const uint4* uf = (const uint4*)u;          // row = 8 uint4 (128 fp8)
    uint4 self = uf[node * 8 + lane];
    f16x2 z = {(_Float16)0.f, (_Float16)0.f};
    f16x2 la0 = z, ha0 = z, la1 = z, ha1 = z, la2 = z, ha2 = z, la3 = z, ha3 = z;
    f16x2 lb0 = z, hb0 = z, lb1 = z, hb1 = z, lb2 = z, hb2 = z, lb3 = z, hb3 = z;
    DECO(self.x, la0, ha0) DECO(self.y, la1, ha1) DECO(self.z, la2, ha2) DECO(self.w, la3, ha3)
    int n = cnti[node];
    const int* ci = colidx + rowptr[node];
    int j = 0;
    for (; j + 4 <= n; j += 4) {
        uint4 va = uf[ci[j] * 8 + lane];
        uint4 vb = uf[ci[j + 1] * 8 + lane];
        uint4 vc = uf[ci[j + 2] * 8 + lane];
        uint4 vd = uf[ci[j + 3] * 8 + lane];
        DECO(va.x, la0, ha0) DECO(va.y, la1, ha1) DECO(va.z, la2, ha2) DECO(va.w, la3, ha3)
        DECO(vb.x, lb0, hb0) DECO(vb.y, lb1, hb1) DECO(vb.z, lb2, hb2) DECO(vb.w, lb3, hb3)
        DECO(vc.x, la0, ha0) DECO(vc.y, la1, ha1) DECO(vc.z, la2, ha2) DECO(vc.w, la3, ha3)
        DECO(vd.x, lb0, hb0) DECO(vd.y, lb1, hb1) DECO(vd.z, lb2, hb2) DECO(vd.w, lb3, hb3)
    }
    for (; j < n; ++j) {
        uint4 va = uf[ci[j] * 8 + lane];
        DECO(va.x, la0, ha0) DECO(va.y, la1, ha1) DECO(va.z, la2, ha2) DECO(va.w, la3, ha3)
    }
    la0 += lb0; ha0 += hb0; la1 += lb1; ha1 += hb1;
    la2 += lb2; ha2 += hb2; la3 += lb3; ha3 += hb3;
    float d = dinv[node] * 16.0f;   // *256 (decode) / 16 (encode scale)
    uint4 o1, o2;
    o1.x = pack_bf16x2((float)la0[0] * d, (float)ha0[0] * d);
    o1.y = pack_bf16x2((float)la0[1] * d, (float)ha0[1] * d);
    o1.z = pack_bf16x2((float)la1[0] * d, (float)ha1[0] * d);
    o1.w = pack_bf16x2((float)la1[1] * d, (float)ha1[1] * d);
    o2.x = pack_bf16x2((float)la2[0] * d, (float)ha2[0] * d);
    o2.y = pack_bf16x2((float)la2[1] * d, (float)ha2[1] * d);
    o2.z = pack_bf16x2((float)la3[0] * d, (float)ha3[0] * d);
    o2.w = pack_bf16x2((float)la3[1] * d, (float)ha3[1] * d);
    *(uint4*)&s2[node * 64 + lane * 8] = o1;
    *(uint4*)&s2[node * 64 + lane * 8 + 4] = o2;
}

// ---- MFMA GEMM: h = relu(A@W + bias); AF16: f16 inputs; EPI 0: out fp8(16*dinv*h); 1: bf16 ----
template<int K, int EPI, int AF16>
__global__ __launch_bounds__(256) void k_gemm_mfma(const unsigned short* __restrict__ Ab,
        const unsigned short* __restrict__ wt, const float* __restrict__ dinv,
        const float* __restrict__ bias, void* __restrict__ outp) {
    constexpr int KS = K / 32;
    constexpr int SLOTS = K / 8;
    __shared__ __align__(16) unsigned short wlds[128 * K];
    char* lb = (char*)wlds;
    for (int c = threadIdx.x; c < 128 * SLOTS; c += 256) {
        int n = c / SLOTS, s = c - n * SLOTS;
        *(uint4*)(lb + n * (2 * K) + ((s ^ (n & 7)) << 4)) = *(const uint4*)(wt + c * 8);
    }
    __syncthreads();
    int lane = threadIdx.x & 63;
    int w = threadIdx.x >> 6;
    int r0 = blockIdx.x * 64 + w * 16;
    int arow = r0 + (lane & 15);
    if (arow >= NN) arow = NN - 1;
    bf16x8 af[KS];
    #pragma unroll
    for (int ks = 0; ks < KS; ++ks)
        af[ks] = *(const bf16x8*)&Ab[(long)arow * K + ks * 32 + (lane >> 4) * 8];
    f32x4 acc[8];
    #pragma unroll
    for (int t = 0; t < 8; ++t) acc[t] = (f32x4){0.f, 0.f, 0.f, 0.f};
    #pragma unroll
    for (int ks = 0; ks < KS; ++ks) {
        #pragma unroll
        for (int t = 0; t < 8; ++t) {
            int n = t * 16 + (lane & 15);
            int slot = ks * 4 + (lane >> 4);
            bf16x8 braw = *(const bf16x8*)(lb + n * (2 * K) + ((slot ^ (n & 7)) << 4));
            if constexpr (AF16) {
                union { bf16x8 r; f16x8 h; } ca, cb;
                ca.r = af[ks]; cb.r = braw;
                acc[t] = __builtin_amdgcn_mfma_f32_16x16x32_f16(ca.h, cb.h, acc[t], 0, 0, 0);
            } else {
                acc[t] = __builtin_amdgcn_mfma_f32_16x16x32_bf16(af[ks], braw, acc[t], 0, 0, 0);
            }
        }
    }
    float bv[8];
    #pragma unroll
    for (int t = 0; t < 8; ++t) bv[t] = bias[t * 16 + (lane & 15)];
    #pragma unroll
    for (int r = 0; r < 4; ++r) {
        long row = r0 + (lane >> 4) * 4 + r;
        if (row >= NN) continue;
        float d = dinv[row];
        #pragma unroll
        for (int t = 0; t < 8; ++t) {
            float val = fmaxf(acc[t][r] + bv[t], 0.f);
            int col = t * 16 + (lane & 15);
            if (EPI == 0)
                ((unsigned char*)outp)[row * 128 + col] = (unsigned char)f2fp8(val * (16.0f * d));
            else
                ((unsigned short*)outp)[row * 128 + col] = f2bf(val);
        }
    }
}

// ---- segmented mean pool over bf16 h2: 4 waves per graph ----
__global__ __launch_bounds__(256) void k_poolmean(const unsigned* __restrict__ h,
        const int* __restrict__ seg_end, float* __restrict__ hg) {
    __shared__ float part[3][128];
    int g = blockIdx.x;
    int w = threadIdx.x >> 6, t = threadIdx.x & 63;
    int s = (g == 0) ? 0 : seg_end[g - 1];
    int e = seg_end[g];
    float a0 = 0.f, a1 = 0.f;
    for (int i = s + w; i < e; i += 4) {
        unsigned u = h[(long)i * 64 + t];
        a0 += __uint_as_float(u << 16);
        a1 += __uint_as_float(u & 0xffff0000u);
    }
    if (w) { part[w - 1][t * 2] = a0; part[w - 1][t * 2 + 1] = a1; }
    __syncthreads();
    if (w == 0) {
        a0 += part[0][t * 2] + part[1][t * 2] + part[2][t * 2];
        a1 += part[0][t * 2 + 1] + part[1][t * 2 + 1] + part[2][t * 2 + 1];
        float inv = (e > s) ? 1.0f / (float)(e - s) : 0.f;
        float2 o = { a0 * inv, a1 * inv };
        *(float2*)&hg[g * 128 + t * 2] = o;
    }
}

// ---- fused decoder head: mu/lv/z + 2 MLP layers; one block (128 thr) per graph ----
// p2 output stored as f16 for the MFMA dec3
__global__ __launch_bounds__(128) void k_decfused(const float* __restrict__ hg,
        const float* __restrict__ Wmu, const float* __restrict__ bmu,
        const float* __restrict__ Wlv, const float* __restrict__ blv,
        const float* __restrict__ eps,
        const float* __restrict__ D1, const float* __restrict__ d1,
        const float* __restrict__ D2, const float* __restrict__ d2,
        float* __restrict__ mu_o, float* __restrict__ lv_o,
        unsigned short* __restrict__ p2out) {
    __shared__ float row[128], mlv[128], zr[64], p1[128];
    int g = blockIdx.x, t = threadIdx.x;
    row[t] = hg[g * 128 + t];
    __syncthreads();
    if (t < 64) {
        float acc = bmu[t];
        for (int k = 0; k < 128; ++k) acc += row[k] * Wmu[k * 64 + t];
        mlv[t] = acc;
    } else {
        int t2 = t - 64;
        float acc = blv[t2];
        for (int k = 0; k < 128; ++k) acc += row[k] * Wlv[k * 64 + t2];
        mlv[64 + t2] = acc;
    }
    __syncthreads();
    if (t < 64) {
        float mu = mlv[t], lv = mlv[64 + t];
        mu_o[g * 64 + t] = mu;
        lv_o[g * 64 + t] = lv;
        zr[t] = mu + eps[g * 64 + t] * expf(0.5f * lv);
    }
    __syncthreads();
    float acc = d1[t];
    for (int k = 0; k < 64; ++k) acc += zr[k] * D1[k * 128 + t];
    p1[t] = fmaxf(acc, 0.f);
    __syncthreads();
    acc = d2[t];
    for (int k = 0; k < 128; ++k) acc += p1[k] * D2[k * 128 + t];
    p2out[g * 128 + t] = (unsigned short)__half_as_ushort(__float2half(fmaxf(acc, 0.f)));
}

// ---- probs = sigmoid(p2 @ D3 + d3) via MFMA f16; no LDS; 64x64 tiles ----
__global__ __launch_bounds__(256) void k_dec3m(const unsigned short* __restrict__ Ab,
        const unsigned short* __restrict__ Wt, const float* __restrict__ b,
        float* __restrict__ out) {
    int lane = threadIdx.x & 63;
    int w = threadIdx.x >> 6;
    int r0 = blockIdx.x * 64 + w * 16;          // m in 0..511
    int c0 = blockIdx.y * 64;                    // n in 0..8127
    int arow = r0 + (lane & 15);
    f16x8 af[4];
    #pragma unroll
    for (int ks = 0; ks < 4; ++ks) {
        union { bf16x8 r; f16x8 h; } ca;
        ca.r = *(const bf16x8*)&Ab[arow * 128 + ks * 32 + (lane >> 4) * 8];
        af[ks] = ca.h;
    }
    f32x4 acc[4];
    #pragma unroll
    for (int nt = 0; nt < 4; ++nt) acc[nt] = (f32x4){0.f, 0.f, 0.f, 0.f};
    #pragma unroll
    for (int nt = 0; nt < 4; ++nt) {
        long n = c0 + nt * 16 + (lane & 15);
        #pragma unroll
        for (int ks = 0; ks < 4; ++ks) {
            union { bf16x8 r; f16x8 h; } cb;
            cb.r = *(const bf16x8*)&Wt[n * 128 + ks * 32 + (lane >> 4) * 8];
            acc[nt] = __builtin_amdgcn_mfma_f32_16x16x32_f16(af[ks], cb.h, acc[nt], 0, 0, 0);
        }
    }
    #pragma unroll
    for (int nt = 0; nt < 4; ++nt) {
        int col = c0 + nt * 16 + (lane & 15);
        float bias = b[col];
        #pragma unroll
        for (int r = 0; r < 4; ++r) {
            int row = r0 + (lane >> 4) * 4 + r;
            float v = acc[nt][r] + bias;
            out[(long)row * OUTS + col] = 1.f / (1.f + expf(-v));
        }
    }
}

// ---- build symmetric adjacency ----
__global__ __launch_bounds__(256) void k_adj(const float* __restrict__ probs, float* __restrict__ adj) {
    int t = blockIdx.x * 256 + threadIdx.x;
    int g = t >> 12;
    int rem = t & 4095;
    int r = rem >> 5;
    int c0 = (rem & 31) * 4;
    const float* pg = &probs[g * OUTS];
    float4 o;
    float* op = (float*)&o;
    #pragma unroll
    for (int j = 0; j < 4; ++j) {
        int c = c0 + j;
        if (c == r) { op[j] = 0.f; continue; }
        int a = c < r ? c : r;
        int b = c < r ? r : c;
        int k = a * (255 - a) / 2 + (b - a - 1);
        op[j] = pg[k];
    }
    *(float4*)&adj[(long)t * 4] = o;
}

extern "C" void kernel_launch(void* const* d_in, const int* in_sizes, int n_in,
                              void* d_out, int out_size, void* d_ws, size_t ws_size,
                              hipStream_t stream) {
    const float* x   = (const float*)d_in[0];
    const int*   ei  = (const int*)d_in[1];
    const int* batch = (const int*)d_in[2];
    const float* eps = (const float*)d_in[3];
    const float* W1  = (const float*)d_in[4];
    const float* b1  = (const float*)d_in[5];
    const float* W2  = (const float*)d_in[6];
    const float* b2  = (const float*)d_in[7];
    const float* Wmu = (const float*)d_in[8];
    const float* bmu = (const float*)d_in[9];
    const float* Wlv = (const float*)d_in[10];
    const float* blv = (const float*)d_in[11];
    const float* D1  = (const float*)d_in[12];
    const float* d1  = (const float*)d_in[13];
    const float* D2  = (const float*)d_in[14];
    const float* d2  = (const float*)d_in[15];
    const float* D3  = (const float*)d_in[16];
    const float* d3  = (const float*)d_in[17];

    const int* esrc = ei;
    const int* edst = ei + NE;

    float* out  = (float*)d_out;
    float* mu_o = out + 8388608;
    float* lv_o = mu_o + 32768;

    // --- CSR + small scratch in d_out (region fully overwritten by k_adj at the end) ---
    int*   colidx   = (int*)out;                  // 1,600,000
    int*   cnti     = colidx + 1600000;           // 100,000
    int*   rowptr   = cnti + 100000;              // 100,000
    int*   seg_end  = rowptr + 100000;            // 512
    float* dinv     = (float*)(seg_end + 512);    // 100,000
    int*   scanhist = (int*)(dinv + 100000);      // 196*197 = 38,612
    int*   bucketbase = scanhist + 38612;         // 196
    unsigned short* wt3t = (unsigned short*)(bucketbase + 256);  // 1,040,384 u16 (ends ~2.46M floats << 8.39M)

    // --- ws layout (float-unit offsets) ---
    float* ws = (float*)d_ws;
    unsigned* u1u = (unsigned*)ws;                         // 3.2M uints (f16x2)
    unsigned* s1u = u1u + 3200000;                         // 3.2M uints (f16x2)
    unsigned char* u2b = (unsigned char*)(ws + 6400000);   // 12.8M bytes (fp8)
    unsigned* s2u = (unsigned*)(ws + 9600000);             // 6.4M uints (bf16x2)
    unsigned* h2b = (unsigned*)(ws + 16000000);            // 6.4M uints (bf16x2)
    unsigned short* wt1 = (unsigned short*)(ws + 22400000);   // 8192 u16 (f16)
    unsigned short* wt2 = wt1 + 8192;                         // 16384 u16 (bf16)
    int* tmp = (int*)(ws + 22420000);                      // 1.6M+ ints
    // decoder scratch aliases u1/s1 (dead after gemm1)
    float* hg = ws;                                        // 65,536 floats
    unsigned short* p2b = (unsigned short*)(hg + 65536);   // 65,536 u16
    float* probs = hg + 131072;                            // 4.16M floats

    // ---- CSR build: zero global atomics ----
    k_part<<<NPB, 512, 0, stream>>>(esrc, edst, tmp, scanhist);
    k_btotseg<<<392, 256, 0, stream>>>(scanhist, bucketbase, batch, seg_end);
    k_fill2<<<NB2, 1024, 0, stream>>>(bucketbase, scanhist, tmp, colidx, cnti, rowptr, dinv);

    // ---- weight conversions ----
    k_wtall<<<96, 256, 0, stream>>>(W1, W2, wt1, wt2);
    dim3 gt(254, 4);
    k_wt3t<<<gt, 256, 0, stream>>>(D3, wt3t);

    // ---- conv1 (f16 gather in 64-ch x-space, then f16 MFMA GEMM -> fp8) ----
    k_scale_x<<<12500, 256, 0, stream>>>(x, dinv, u1u);
    k_gather1<<<3125, 256, 0, stream>>>(rowptr, cnti, colidx, u1u, dinv, s1u);
    k_gemm_mfma<64, 0, 1><<<1563, 256, 0, stream>>>((const unsigned short*)s1u, wt1, dinv, b1, u2b);

    // ---- conv2 (fp8 packed-decode gather, then bf16 MFMA GEMM) ----
    k_gather2<<<3125, 256, 0, stream>>>(rowptr, cnti, colidx, (const unsigned*)u2b, dinv, s2u);
    k_gemm_mfma<128, 1, 0><<<1563, 256, 0, stream>>>((const unsigned short*)s2u, wt2, dinv, b2, h2b);

    // ---- pool + fused decoder head ----
    k_poolmean<<<NG, 256, 0, stream>>>(h2b, seg_end, hg);
    k_decfused<<<NG, 128, 0, stream>>>(hg, Wmu, bmu, Wlv, blv, eps, D1, d1, D2, d2,
                                       mu_o, lv_o, p2b);

    // ---- MFMA decoder output + adjacency ----
    dim3 g3(8, 127);
    k_dec3m<<<g3, 256, 0, stream>>>(p2b, wt3t, d3, probs);
    k_adj<<<8192, 256, 0, stream>>>(probs, out);
}

// Round 14
// 205.740 us; speedup vs baseline: 1.5624x; 1.0722x over previous
//
#include <hip/hip_runtime.h>
#include <hip/hip_fp16.h>

#define NN 100000
#define NE 1600000
#define NG 512
#define OUTS 8128
#define NB2 196     // coarse buckets of 512 nodes (196*512 = 100352 >= NN)
#define CHUNK 8192
#define NPB 196     // ceil(NE/CHUNK)

typedef short bf16x8 __attribute__((ext_vector_type(8)));
typedef _Float16 f16x8 __attribute__((ext_vector_type(8)));
typedef _Float16 f16x2 __attribute__((ext_vector_type(2)));
typedef float f32x4 __attribute__((ext_vector_type(4)));

__device__ __forceinline__ unsigned pack_bf16x2(float a, float b) {
    unsigned ua = __float_as_uint(a);
    unsigned ub = __float_as_uint(b);
    ua = (ua + 0x7fffu + ((ua >> 16) & 1u)) >> 16;
    ub = (ub + 0x7fffu + ((ub >> 16) & 1u)) >> 16;
    return ua | (ub << 16);
}
__device__ __forceinline__ unsigned short f2bf(float f) {
    unsigned u = __float_as_uint(f);
    u = (u + 0x7fffu + ((u >> 16) & 1u)) >> 16;
    return (unsigned short)u;
}
// f32 pair -> packed f16x2 (RTZ), as raw uint
__device__ __forceinline__ unsigned cvt_pkrtz_u(float a, float b) {
    auto h = __builtin_amdgcn_cvt_pkrtz(a, b);
    union { decltype(h) h2; unsigned u; } c; c.h2 = h; return c.u;
}
__device__ __forceinline__ f16x2 u2h(unsigned u) { union { unsigned u; f16x2 h; } c; c.u = u; return c.h; }

// e4m3 encode, f >= 0 (relu'd): e4m3(v) == f16(v/256) with 10->3 mantissa round
__device__ __forceinline__ unsigned f2fp8(float f) {
    unsigned h = (unsigned)__half_as_ushort(__float2half(f * 0.00390625f));
    return (h + 0x3Fu + ((h >> 7) & 1u)) >> 7;
}
// e4m3 encode, signed
__device__ __forceinline__ unsigned f2fp8s(float f) {
    unsigned h = (unsigned)__half_as_ushort(__float2half(f * 0.00390625f));
    unsigned s = (h >> 8) & 0x80u;
    unsigned mag = h & 0x7fffu;
    return s | ((mag + 0x3Fu + ((mag >> 7) & 1u)) >> 7);
}

// unsigned packed decode (relu'd data): 4 fp8 -> two f16x2 accumulators
#define DECO(W, LO, HI) { LO += u2h(((W) & 0x007f007fu) << 7); HI += u2h(((W) & 0x7f007f00u) >> 1); }
// signed packed decode
#define DECOS(W, LO, HI) { \
    LO += u2h((((W) & 0x007f007fu) << 7) | (((W) & 0x00800080u) << 8)); \
    HI += u2h((((W) & 0x7f007f00u) >> 1) | ((W) & 0x80008000u)); }

// ---- phase 1: partition an 8192-edge chunk into 196 coarse buckets (512 threads) ----
__global__ __launch_bounds__(512) void k_part(const int* __restrict__ src, const int* __restrict__ dst,
        int* __restrict__ tmp, int* __restrict__ scanhist) {
    __shared__ int hist[NB2], cur[NB2], scan[256];
    int p = blockIdx.x, t = threadIdx.x;
    int e0 = p * CHUNK;
    int e1 = min(e0 + CHUNK, NE);
    for (int i = t; i < NB2; i += 512) hist[i] = 0;
    __syncthreads();
    for (int e = e0 + t; e < e1; e += 512)
        atomicAdd(&hist[dst[e] >> 9], 1);
    __syncthreads();
    int h = 0;
    if (t < 256) { h = (t < NB2) ? hist[t] : 0; scan[t] = h; }
    __syncthreads();
    for (int off = 1; off < 256; off <<= 1) {
        int v = (t < 256 && t >= off) ? scan[t - off] : 0;
        __syncthreads();
        if (t < 256) scan[t] += v;
        __syncthreads();
    }
    if (t < NB2) {
        int excl = scan[t] - h;
        cur[t] = excl;
        scanhist[p * (NB2 + 1) + t] = excl;
    }
    if (t == 0) scanhist[p * (NB2 + 1) + NB2] = e1 - e0;
    __syncthreads();
    for (int e = e0 + t; e < e1; e += 512) {
        int d = dst[e];
        int b = d >> 9;
        int r = atomicAdd(&cur[b], 1);          // LDS atomic only
        tmp[e0 + r] = (src[e] << 9) | (d & 511);
    }
}

// ---- block 0: bucket totals + scan -> bucketbase; blocks 1..: segment ends ----
__global__ __launch_bounds__(256) void k_btotseg(const int* __restrict__ scanhist,
        int* __restrict__ bucketbase, const int* __restrict__ batch, int* __restrict__ seg_end) {
    if (blockIdx.x == 0) {
        __shared__ int sc[256];
        int b = threadIdx.x;
        int tot = 0;
        if (b < NB2) {
            for (int p = 0; p < NPB; ++p)
                tot += scanhist[p * (NB2 + 1) + b + 1] - scanhist[p * (NB2 + 1) + b];
        }
        sc[b] = tot;
        __syncthreads();
        for (int off = 1; off < 256; off <<= 1) {
            int v = (b >= off) ? sc[b - off] : 0;
            __syncthreads();
            sc[b] += v;
            __syncthreads();
        }
        if (b < NB2) bucketbase[b] = sc[b] - tot;
    } else {
        int i = (blockIdx.x - 1) * 256 + threadIdx.x;
        if (i >= NN) return;
        int b = batch[i];
        int bn = (i == NN - 1) ? NG : batch[i + 1];
        for (int g = b; g < bn; ++g) seg_end[g] = i + 1;
        if (i == 0) {
            for (int g = 0; g < b; ++g) seg_end[g] = 0;
        }
    }
}

// ---- phase 2: per-bucket count+scan+place; emits cnti/rowptr/dinv/colidx AND u1b = fp8(x*dinv) ----
__global__ __launch_bounds__(1024) void k_fill2(const int* __restrict__ bucketbase,
        const int* __restrict__ scanhist, const int* __restrict__ tmp,
        int* __restrict__ colidx, int* __restrict__ cnti, int* __restrict__ rowptr,
        float* __restrict__ dinv, const float* __restrict__ x, unsigned* __restrict__ u1b) {
    __shared__ int lc[512], rb[512], sc[256];
    __shared__ float ldv[512];
    int b = blockIdx.x, t = threadIdx.x;
    int n0 = b << 9;
    if (t < 512) lc[t] = 0;
    __syncthreads();
    int w = t >> 6, lane = t & 63;              // w in 0..15
    // count phase
    for (int p = w; p < NPB; p += 16) {
        int s0 = scanhist[p * (NB2 + 1) + b];
        int s1 = scanhist[p * (NB2 + 1) + b + 1];
        int base = p * CHUNK;
        for (int i = s0 + lane; i < s1; i += 64)
            atomicAdd(&lc[tmp[base + i] & 511], 1);
    }
    __syncthreads();
    // scan 512 via 256 pair-partials
    int v0 = 0, v1 = 0, s = 0;
    if (t < 256) { v0 = lc[2 * t]; v1 = lc[2 * t + 1]; s = v0 + v1; sc[t] = s; }
    __syncthreads();
    for (int off = 1; off < 256; off <<= 1) {
        int xv = (t < 256 && t >= off) ? sc[t - off] : 0;
        __syncthreads();
        if (t < 256) sc[t] += xv;
        __syncthreads();
    }
    if (t < 256) {
        int excl = sc[t] - s;
        int base0 = bucketbase[b];
        rb[2 * t] = base0 + excl;
        rb[2 * t + 1] = base0 + excl + v0;
        float dv0 = rsqrtf((float)v0 + 1.0f);
        float dv1 = rsqrtf((float)v1 + 1.0f);
        ldv[2 * t] = dv0;
        ldv[2 * t + 1] = dv1;
        int node0 = n0 + 2 * t;
        if (node0 < NN) {
            cnti[node0] = v0;
            rowptr[node0] = base0 + excl;
            dinv[node0] = dv0;
        }
        if (node0 + 1 < NN) {
            cnti[node0 + 1] = v1;
            rowptr[node0 + 1] = base0 + excl + v0;
            dinv[node0 + 1] = dv1;
        }
    }
    __syncthreads();
    if (t < 512) lc[t] = 0;
    __syncthreads();
    // place phase
    for (int p = w; p < NPB; p += 16) {
        int s0 = scanhist[p * (NB2 + 1) + b];
        int s1 = scanhist[p * (NB2 + 1) + b + 1];
        int base = p * CHUNK;
        for (int i = s0 + lane; i < s1; i += 64) {
            int v = tmp[base + i];
            int dl = v & 511;
            int pos = atomicAdd(&lc[dl], 1);    // LDS atomic only
            colidx[rb[dl] + pos] = v >> 9;
        }
    }
    // x-scale phase: u1b[node][c] = fp8s(x*dinv), 16 uints (64ch) per node
    for (int i = t; i < 512 * 16; i += 1024) {
        int local = i >> 4, c = i & 15;
        int node = n0 + local;
        if (node >= NN) continue;
        float4 xv = *(const float4*)&x[(long)node * 64 + c * 4];
        float d = ldv[local];
        unsigned o = f2fp8s(xv.x * d) | (f2fp8s(xv.y * d) << 8)
                   | (f2fp8s(xv.z * d) << 16) | (f2fp8s(xv.w * d) << 24);
        u1b[node * 16 + c] = o;
    }
}

// ---- all weight conversions: wt1 f16 T, wt2 bf16 T, wt3t = D3^T f16 ----
__global__ __launch_bounds__(256) void k_wtall(const float* __restrict__ W1,
        const float* __restrict__ W2, const float* __restrict__ D3,
        unsigned short* __restrict__ wt1, unsigned short* __restrict__ wt2,
        unsigned short* __restrict__ wt3t) {
    __shared__ float tile[32][33];
    int blk = blockIdx.x;
    if (blk < 96) {
        int i = blk * 256 + threadIdx.x;
        if (i < 8192) {                          // wt1: [128][64] f16, transposed
            int n = i >> 6, k = i & 63;
            wt1[i] = (unsigned short)__half_as_ushort(__float2half(W1[k * 128 + n]));
        } else {                                 // wt2: [128][128] bf16, transposed
            int e = i - 8192;
            int n = e >> 7, k = e & 127;
            wt2[e] = f2bf(W2[k * 128 + n]);
        }
    } else {
        int bb = blk - 96;                       // 0..1015
        int n0 = (bb % 254) * 32, k0 = (bb / 254) * 32;
        for (int i = threadIdx.x; i < 1024; i += 256) {
            int kk = i >> 5, nn = i & 31;
            tile[kk][nn] = D3[(long)(k0 + kk) * OUTS + n0 + nn];
        }
        __syncthreads();
        for (int i = threadIdx.x; i < 1024; i += 256) {
            int nn = i >> 5, kk = i & 31;
            wt3t[(long)(n0 + nn) * 128 + k0 + kk] =
                (unsigned short)__half_as_ushort(__float2half(tile[kk][nn]));
        }
    }
}

// ---- gather1: s1 = f16(dinv_n * (u1[n] + sum u1[src])), 64ch signed fp8 in ----
// 4 lanes/node, uint4 (16ch) per lane, 4-deep unroll
__global__ __launch_bounds__(256) void k_gather1(const int* __restrict__ rowptr,
        const int* __restrict__ cnti, const int* __restrict__ colidx,
        const unsigned* __restrict__ u, const float* __restrict__ dinv,
        unsigned* __restrict__ s1) {
    int node = blockIdx.x * 64 + (threadIdx.x >> 2);
    if (node >= NN) return;
    int lane = threadIdx.x & 3;
    const uint4* uf = (const uint4*)u;          // row = 4 uint4 (64 fp8)
    uint4 self = uf[node * 4 + lane];
    f16x2 z = {(_Float16)0.f, (_Float16)0.f};
    f16x2 la0 = z, ha0 = z, la1 = z, ha1 = z, la2 = z, ha2 = z, la3 = z, ha3 = z;
    f16x2 lb0 = z, hb0 = z, lb1 = z, hb1 = z, lb2 = z, hb2 = z, lb3 = z, hb3 = z;
    DECOS(self.x, la0, ha0) DECOS(self.y, la1, ha1) DECOS(self.z, la2, ha2) DECOS(self.w, la3, ha3)
    int n = cnti[node];
    const int* ci = colidx + rowptr[node];
    int j = 0;
    for (; j + 4 <= n; j += 4) {
        uint4 va = uf[ci[j] * 4 + lane];
        uint4 vb = uf[ci[j + 1] * 4 + lane];
        uint4 vc = uf[ci[j + 2] * 4 + lane];
        uint4 vd = uf[ci[j + 3] * 4 + lane];
        DECOS(va.x, la0, ha0) DECOS(va.y, la1, ha1) DECOS(va.z, la2, ha2) DECOS(va.w, la3, ha3)
        DECOS(vb.x, lb0, hb0) DECOS(vb.y, lb1, hb1) DECOS(vb.z, lb2, hb2) DECOS(vb.w, lb3, hb3)
        DECOS(vc.x, la0, ha0) DECOS(vc.y, la1, ha1) DECOS(vc.z, la2, ha2) DECOS(vc.w, la3, ha3)
        DECOS(vd.x, lb0, hb0) DECOS(vd.y, lb1, hb1) DECOS(vd.z, lb2, hb2) DECOS(vd.w, lb3, hb3)
    }
    for (; j < n; ++j) {
        uint4 va = uf[ci[j] * 4 + lane];
        DECOS(va.x, la0, ha0) DECOS(va.y, la1, ha1) DECOS(va.z, la2, ha2) DECOS(va.w, la3, ha3)
    }
    la0 += lb0; ha0 += hb0; la1 += lb1; ha1 += hb1;
    la2 += lb2; ha2 += hb2; la3 += lb3; ha3 += hb3;
    float d = dinv[node] * 256.0f;              // *256 decode scale
    uint4 o1, o2;
    o1.x = cvt_pkrtz_u((float)la0[0] * d, (float)ha0[0] * d);   // ch0,ch1
    o1.y = cvt_pkrtz_u((float)la0[1] * d, (float)ha0[1] * d);   // ch2,ch3
    o1.z = cvt_pkrtz_u((float)la1[0] * d, (float)ha1[0] * d);
    o1.w = cvt_pkrtz_u((float)la1[1] * d, (float)ha1[1] * d);
    o2.x = cvt_pkrtz_u((float)la2[0] * d, (float)ha2[0] * d);
    o2.y = cvt_pkrtz_u((float)la2[1] * d, (float)ha2[1] * d);
    o2.z = cvt_pkrtz_u((float)la3[0] * d, (float)ha3[0] * d);
    o2.w = cvt_pkrtz_u((float)la3[1] * d, (float)ha3[1] * d);
    *(uint4*)&s1[node * 32 + lane * 8] = o1;
    *(uint4*)&s1[node * 32 + lane * 8 + 4] = o2;
}

// ---- gather2: s2 = bf16(16*dinv_n * sum fp8rows), 128ch fp8 (relu'd, unsigned) ----
// 8 lanes/node, uint4 (16ch) per lane, 4-deep unroll
__global__ __launch_bounds__(256) void k_gather2(const int* __restrict__ rowptr,
        const int* __restrict__ cnti, const int* __restrict__ colidx,
        const unsigned* __restrict__ u, const float* __restrict__ dinv,
        unsigned* __restrict__ s2) {
    int node = blockIdx.x * 32 + (threadIdx.x >> 3);
    int lane = threadIdx.x & 7;
    const uint4* uf = (const uint4*)u;          // row = 8 uint4 (128 fp8)
    uint4 self = uf[node * 8 + lane];
    f16x2 z = {(_Float16)0.f, (_Float16)0.f};
    f16x2 la0 = z, ha0 = z, la1 = z, ha1 = z, la2 = z, ha2 = z, la3 = z, ha3 = z;
    f16x2 lb0 = z, hb0 = z, lb1 = z, hb1 = z, lb2 = z, hb2 = z, lb3 = z, hb3 = z;
    DECO(self.x, la0, ha0) DECO(self.y, la1, ha1) DECO(self.z, la2, ha2) DECO(self.w, la3, ha3)
    int n = cnti[node];
    const int* ci = colidx + rowptr[node];
    int j = 0;
    for (; j + 4 <= n; j += 4) {
        uint4 va = uf[ci[j] * 8 + lane];
        uint4 vb = uf[ci[j + 1] * 8 + lane];
        uint4 vc = uf[ci[j + 2] * 8 + lane];
        uint4 vd = uf[ci[j + 3] * 8 + lane];
        DECO(va.x, la0, ha0) DECO(va.y, la1, ha1) DECO(va.z, la2, ha2) DECO(va.w, la3, ha3)
        DECO(vb.x, lb0, hb0) DECO(vb.y, lb1, hb1) DECO(vb.z, lb2, hb2) DECO(vb.w, lb3, hb3)
        DECO(vc.x, la0, ha0) DECO(vc.y, la1, ha1) DECO(vc.z, la2, ha2) DECO(vc.w, la3, ha3)
        DECO(vd.x, lb0, hb0) DECO(vd.y, lb1, hb1) DECO(vd.z, lb2, hb2) DECO(vd.w, lb3, hb3)
    }
    for (; j < n; ++j) {
        uint4 va = uf[ci[j] * 8 + lane];
        DECO(va.x, la0, ha0) DECO(va.y, la1, ha1) DECO(va.z, la2, ha2) DECO(va.w, la3, ha3)
    }
    la0 += lb0; ha0 += hb0; la1 += lb1; ha1 += hb1;
    la2 += lb2; ha2 += hb2; la3 += lb3; ha3 += hb3;
    float d = dinv[node] * 16.0f;   // *256 (decode) / 16 (encode scale)
    uint4 o1, o2;
    o1.x = pack_bf16x2((float)la0[0] * d, (float)ha0[0] * d);
    o1.y = pack_bf16x2((float)la0[1] * d, (float)ha0[1] * d);
    o1.z = pack_bf16x2((float)la1[0] * d, (float)ha1[0] * d);
    o1.w = pack_bf16x2((float)la1[1] * d, (float)ha1[1] * d);
    o2.x = pack_bf16x2((float)la2[0] * d, (float)ha2[0] * d);
    o2.y = pack_bf16x2((float)la2[1] * d, (float)ha2[1] * d);
    o2.z = pack_bf16x2((float)la3[0] * d, (float)ha3[0] * d);
    o2.w = pack_bf16x2((float)la3[1] * d, (float)ha3[1] * d);
    *(uint4*)&s2[node * 64 + lane * 8] = o1;
    *(uint4*)&s2[node * 64 + lane * 8 + 4] = o2;
}

// ---- MFMA GEMM: h = relu(A@W + bias); AF16: f16 inputs; EPI 0: out fp8(16*dinv*h); 1: bf16 ----
template<int K, int EPI, int AF16>
__global__ __launch_bounds__(256) void k_gemm_mfma(const unsigned short* __restrict__ Ab,
        const unsigned short* __restrict__ wt, const float* __restrict__ dinv,
        const float* __restrict__ bias, void* __restrict__ outp) {
    constexpr int KS = K / 32;
    constexpr int SLOTS = K / 8;
    __shared__ __align__(16) unsigned short wlds[128 * K];
    char* lb = (char*)wlds;
    for (int c = threadIdx.x; c < 128 * SLOTS; c += 256) {
        int n = c / SLOTS, s = c - n * SLOTS;
        *(uint4*)(lb + n * (2 * K) + ((s ^ (n & 7)) << 4)) = *(const uint4*)(wt + c * 8);
    }
    __syncthreads();
    int lane = threadIdx.x & 63;
    int w = threadIdx.x >> 6;
    int r0 = blockIdx.x * 64 + w * 16;
    int arow = r0 + (lane & 15);
    if (arow >= NN) arow = NN - 1;
    bf16x8 af[KS];
    #pragma unroll
    for (int ks = 0; ks < KS; ++ks)
        af[ks] = *(const bf16x8*)&Ab[(long)arow * K + ks * 32 + (lane >> 4) * 8];
    f32x4 acc[8];
    #pragma unroll
    for (int t = 0; t < 8; ++t) acc[t] = (f32x4){0.f, 0.f, 0.f, 0.f};
    #pragma unroll
    for (int ks = 0; ks < KS; ++ks) {
        #pragma unroll
        for (int t = 0; t < 8; ++t) {
            int n = t * 16 + (lane & 15);
            int slot = ks * 4 + (lane >> 4);
            bf16x8 braw = *(const bf16x8*)(lb + n * (2 * K) + ((slot ^ (n & 7)) << 4));
            if constexpr (AF16) {
                union { bf16x8 r; f16x8 h; } ca, cb;
                ca.r = af[ks]; cb.r = braw;
                acc[t] = __builtin_amdgcn_mfma_f32_16x16x32_f16(ca.h, cb.h, acc[t], 0, 0, 0);
            } else {
                acc[t] = __builtin_amdgcn_mfma_f32_16x16x32_bf16(af[ks], braw, acc[t], 0, 0, 0);
            }
        }
    }
    float bv[8];
    #pragma unroll
    for (int t = 0; t < 8; ++t) bv[t] = bias[t * 16 + (lane & 15)];
    #pragma unroll
    for (int r = 0; r < 4; ++r) {
        long row = r0 + (lane >> 4) * 4 + r;
        if (row >= NN) continue;
        float d = dinv[row];
        #pragma unroll
        for (int t = 0; t < 8; ++t) {
            float val = fmaxf(acc[t][r] + bv[t], 0.f);
            int col = t * 16 + (lane & 15);
            if (EPI == 0)
                ((unsigned char*)outp)[row * 128 + col] = (unsigned char)f2fp8(val * (16.0f * d));
            else
                ((unsigned short*)outp)[row * 128 + col] = f2bf(val);
        }
    }
}

// ---- fused: segmented mean pool + mu/lv/z + 2 MLP layers; one block (256 thr) per graph ----
__global__ __launch_bounds__(256) void k_pooldec(const unsigned* __restrict__ h,
        const int* __restrict__ seg_end,
        const float* __restrict__ Wmu, const float* __restrict__ bmu,
        const float* __restrict__ Wlv, const float* __restrict__ blv,
        const float* __restrict__ eps,
        const float* __restrict__ D1, const float* __restrict__ d1,
        const float* __restrict__ D2, const float* __restrict__ d2,
        float* __restrict__ mu_o, float* __restrict__ lv_o,
        unsigned short* __restrict__ p2out) {
    __shared__ float part[3][128];
    __shared__ float row[128], mlv[128], zr[64], p1[128];
    int g = blockIdx.x;
    int w = threadIdx.x >> 6, t64 = threadIdx.x & 63;
    int s = (g == 0) ? 0 : seg_end[g - 1];
    int e = seg_end[g];
    float a0 = 0.f, a1 = 0.f;
    for (int i = s + w; i < e; i += 4) {
        unsigned u = h[(long)i * 64 + t64];
        a0 += __uint_as_float(u << 16);
        a1 += __uint_as_float(u & 0xffff0000u);
    }
    if (w) { part[w - 1][t64 * 2] = a0; part[w - 1][t64 * 2 + 1] = a1; }
    __syncthreads();
    if (w == 0) {
        a0 += part[0][t64 * 2] + part[1][t64 * 2] + part[2][t64 * 2];
        a1 += part[0][t64 * 2 + 1] + part[1][t64 * 2 + 1] + part[2][t64 * 2 + 1];
        float inv = (e > s) ? 1.0f / (float)(e - s) : 0.f;
        row[t64 * 2] = a0 * inv;
        row[t64 * 2 + 1] = a1 * inv;
    }
    __syncthreads();
    int t = threadIdx.x;
    if (t < 64) {
        float acc = bmu[t];
        for (int k = 0; k < 128; ++k) acc += row[k] * Wmu[k * 64 + t];
        mlv[t] = acc;
    } else if (t < 128) {
        int t2 = t - 64;
        float acc = blv[t2];
        for (int k = 0; k < 128; ++k) acc += row[k] * Wlv[k * 64 + t2];
        mlv[64 + t2] = acc;
    }
    __syncthreads();
    if (t < 64) {
        float mu = mlv[t], lv = mlv[64 + t];
        mu_o[g * 64 + t] = mu;
        lv_o[g * 64 + t] = lv;
        zr[t] = mu + eps[g * 64 + t] * expf(0.5f * lv);
    }
    __syncthreads();
    if (t < 128) {
        float acc = d1[t];
        for (int k = 0; k < 64; ++k) acc += zr[k] * D1[k * 128 + t];
        p1[t] = fmaxf(acc, 0.f);
    }
    __syncthreads();
    if (t < 128) {
        float acc = d2[t];
        for (int k = 0; k < 128; ++k) acc += p1[k] * D2[k * 128 + t];
        p2out[g * 128 + t] = (unsigned short)__half_as_ushort(__float2half(fmaxf(acc, 0.f)));
    }
}

// ---- probs = sigmoid(p2 @ D3 + d3) via MFMA f16; no LDS; 64x64 tiles ----
__global__ __launch_bounds__(256) void k_dec3m(const unsigned short* __restrict__ Ab,
        const unsigned short* __restrict__ Wt, const float* __restrict__ b,
        float* __restrict__ out) {
    int lane = threadIdx.x & 63;
    int w = threadIdx.x >> 6;
    int r0 = blockIdx.x * 64 + w * 16;          // m in 0..511
    int c0 = blockIdx.y * 64;                    // n in 0..8127
    int arow = r0 + (lane & 15);
    f16x8 af[4];
    #pragma unroll
    for (int ks = 0; ks < 4; ++ks) {
        union { bf16x8 r; f16x8 h; } ca;
        ca.r = *(const bf16x8*)&Ab[arow * 128 + ks * 32 + (lane >> 4) * 8];
        af[ks] = ca.h;
    }
    f32x4 acc[4];
    #pragma unroll
    for (int nt = 0; nt < 4; ++nt) acc[nt] = (f32x4){0.f, 0.f, 0.f, 0.f};
    #pragma unroll
    for (int nt = 0; nt < 4; ++nt) {
        long n = c0 + nt * 16 + (lane & 15);
        #pragma unroll
        for (int ks = 0; ks < 4; ++ks) {
            union { bf16x8 r; f16x8 h; } cb;
            cb.r = *(const bf16x8*)&Wt[n * 128 + ks * 32 + (lane >> 4) * 8];
            acc[nt] = __builtin_amdgcn_mfma_f32_16x16x32_f16(af[ks], cb.h, acc[nt], 0, 0, 0);
        }
    }
    #pragma unroll
    for (int nt = 0; nt < 4; ++nt) {
        int col = c0 + nt * 16 + (lane & 15);
        float bias = b[col];
        #pragma unroll
        for (int r = 0; r < 4; ++r) {
            int row = r0 + (lane >> 4) * 4 + r;
            float v = acc[nt][r] + bias;
            out[(long)row * OUTS + col] = 1.f / (1.f + expf(-v));
        }
    }
}

// ---- build symmetric adjacency ----
__global__ __launch_bounds__(256) void k_adj(const float* __restrict__ probs, float* __restrict__ adj) {
    int t = blockIdx.x * 256 + threadIdx.x;
    int g = t >> 12;
    int rem = t & 4095;
    int r = rem >> 5;
    int c0 = (rem & 31) * 4;
    const float* pg = &probs[g * OUTS];
    float4 o;
    float* op = (float*)&o;
    #pragma unroll
    for (int j = 0; j < 4; ++j) {
        int c = c0 + j;
        if (c == r) { op[j] = 0.f; continue; }
        int a = c < r ? c : r;
        int b = c < r ? r : c;
        int k = a * (255 - a) / 2 + (b - a - 1);
        op[j] = pg[k];
    }
    *(float4*)&adj[(long)t * 4] = o;
}

extern "C" void kernel_launch(void* const* d_in, const int* in_sizes, int n_in,
                              void* d_out, int out_size, void* d_ws, size_t ws_size,
                              hipStream_t stream) {
    const float* x   = (const float*)d_in[0];
    const int*   ei  = (const int*)d_in[1];
    const int* batch = (const int*)d_in[2];
    const float* eps = (const float*)d_in[3];
    const float* W1  = (const float*)d_in[4];
    const float* b1  = (const float*)d_in[5];
    const float* W2  = (const float*)d_in[6];
    const float* b2  = (const float*)d_in[7];
    const float* Wmu = (const float*)d_in[8];
    const float* bmu = (const float*)d_in[9];
    const float* Wlv = (const float*)d_in[10];
    const float* blv = (const float*)d_in[11];
    const float* D1  = (const float*)d_in[12];
    const float* d1  = (const float*)d_in[13];
    const float* D2  = (const float*)d_in[14];
    const float* d2  = (const float*)d_in[15];
    const float* D3  = (const float*)d_in[16];
    const float* d3  = (const float*)d_in[17];

    const int* esrc = ei;
    const int* edst = ei + NE;

    float* out  = (float*)d_out;
    float* mu_o = out + 8388608;
    float* lv_o = mu_o + 32768;

    // --- CSR + small scratch in d_out (region fully overwritten by k_adj at the end) ---
    int*   colidx   = (int*)out;                  // 1,600,000
    int*   cnti     = colidx + 1600000;           // 100,000
    int*   rowptr   = cnti + 100000;              // 100,000
    int*   seg_end  = rowptr + 100000;            // 512
    float* dinv     = (float*)(seg_end + 512);    // 100,000
    int*   scanhist = (int*)(dinv + 100000);      // 196*197 = 38,612
    int*   bucketbase = scanhist + 38612;         // 196
    unsigned short* wt3t = (unsigned short*)(bucketbase + 256);  // 1,040,384 u16 (ends ~2.46M floats << 8.39M)

    // --- ws layout (float-unit offsets) ---
    float* ws = (float*)d_ws;
    unsigned* u1b = (unsigned*)ws;                         // 1.6M uints (fp8, 16/row)
    unsigned* s1u = (unsigned*)(ws + 3200000);             // 3.2M uints (f16x2)
    unsigned char* u2b = (unsigned char*)(ws + 6400000);   // 12.8M bytes (fp8)
    unsigned* s2u = (unsigned*)(ws + 9600000);             // 6.4M uints (bf16x2)
    unsigned* h2b = (unsigned*)(ws + 16000000);            // 6.4M uints (bf16x2)
    unsigned short* wt1 = (unsigned short*)(ws + 22400000);   // 8192 u16 (f16)
    unsigned short* wt2 = wt1 + 8192;                         // 16384 u16 (bf16)
    int* tmp = (int*)(ws + 22420000);                      // 1.6M+ ints
    // decoder scratch aliases u1b/s1u (dead by then)
    unsigned short* p2b = (unsigned short*)ws;             // 65,536 u16
    float* probs = ws + 65536;                             // 4.16M floats (< s1u end; s1u dead)

    // ---- CSR build + x-scale: zero global atomics ----
    k_part<<<NPB, 512, 0, stream>>>(esrc, edst, tmp, scanhist);
    k_btotseg<<<392, 256, 0, stream>>>(scanhist, bucketbase, batch, seg_end);
    k_fill2<<<NB2, 1024, 0, stream>>>(bucketbase, scanhist, tmp, colidx, cnti, rowptr,
                                      dinv, x, u1b);

    // ---- all weight conversions ----
    k_wtall<<<1112, 256, 0, stream>>>(W1, W2, D3, wt1, wt2, wt3t);

    // ---- conv1 (signed-fp8 gather in 64-ch x-space, then f16 MFMA GEMM -> fp8) ----
    k_gather1<<<1563, 256, 0, stream>>>(rowptr, cnti, colidx, u1b, dinv, s1u);
    k_gemm_mfma<64, 0, 1><<<1563, 256, 0, stream>>>((const unsigned short*)s1u, wt1, dinv, b1, u2b);

    // ---- conv2 (fp8 packed-decode gather, then bf16 MFMA GEMM) ----
    k_gather2<<<3125, 256, 0, stream>>>(rowptr, cnti, colidx, (const unsigned*)u2b, dinv, s2u);
    k_gemm_mfma<128, 1, 0><<<1563, 256, 0, stream>>>((const unsigned short*)s2u, wt2, dinv, b2, h2b);

    // ---- fused pool + decoder head ----
    k_pooldec<<<NG, 256, 0, stream>>>(h2b, seg_end, Wmu, bmu, Wlv, blv, eps,
                                      D1, d1, D2, d2, mu_o, lv_o, p2b);

    // ---- MFMA decoder output + adjacency ----
    dim3 g3(8, 127);
    k_dec3m<<<g3, 256, 0, stream>>>(p2b, wt3t, d3, probs);
    k_adj<<<8192, 256, 0, stream>>>(probs, out);
}

// Round 15
// 200.731 us; speedup vs baseline: 1.6014x; 1.0250x over previous
//
#include <hip/hip_runtime.h>
#include <hip/hip_fp16.h>

#define NN 100000
#define NE 1600000
#define NG 512
#define OUTS 8128
#define NB2 196     // coarse buckets of 512 nodes (196*512 = 100352 >= NN)
#define CHUNK 8192
#define NPB 196     // ceil(NE/CHUNK)

typedef short bf16x8 __attribute__((ext_vector_type(8)));
typedef _Float16 f16x8 __attribute__((ext_vector_type(8)));
typedef _Float16 f16x2 __attribute__((ext_vector_type(2)));
typedef float f32x4 __attribute__((ext_vector_type(4)));

__device__ __forceinline__ unsigned pack_bf16x2(float a, float b) {
    unsigned ua = __float_as_uint(a);
    unsigned ub = __float_as_uint(b);
    ua = (ua + 0x7fffu + ((ua >> 16) & 1u)) >> 16;
    ub = (ub + 0x7fffu + ((ub >> 16) & 1u)) >> 16;
    return ua | (ub << 16);
}
__device__ __forceinline__ unsigned short f2bf(float f) {
    unsigned u = __float_as_uint(f);
    u = (u + 0x7fffu + ((u >> 16) & 1u)) >> 16;
    return (unsigned short)u;
}
// f32 pair -> packed f16x2 (RTZ), as raw uint
__device__ __forceinline__ unsigned cvt_pkrtz_u(float a, float b) {
    auto h = __builtin_amdgcn_cvt_pkrtz(a, b);
    union { decltype(h) h2; unsigned u; } c; c.h2 = h; return c.u;
}
__device__ __forceinline__ f16x2 u2h(unsigned u) { union { unsigned u; f16x2 h; } c; c.u = u; return c.h; }

// e4m3 encode, f >= 0 (relu'd): e4m3(v) == f16(v/256) with 10->3 mantissa round
__device__ __forceinline__ unsigned f2fp8(float f) {
    unsigned h = (unsigned)__half_as_ushort(__float2half(f * 0.00390625f));
    return (h + 0x3Fu + ((h >> 7) & 1u)) >> 7;
}
// e4m3 encode, signed
__device__ __forceinline__ unsigned f2fp8s(float f) {
    unsigned h = (unsigned)__half_as_ushort(__float2half(f * 0.00390625f));
    unsigned s = (h >> 8) & 0x80u;
    unsigned mag = h & 0x7fffu;
    return s | ((mag + 0x3Fu + ((mag >> 7) & 1u)) >> 7);
}

// unsigned packed decode (relu'd data): 4 fp8 -> two f16x2 accumulators
#define DECO(W, LO, HI) { LO += u2h(((W) & 0x007f007fu) << 7); HI += u2h(((W) & 0x7f007f00u) >> 1); }
// signed packed decode
#define DECOS(W, LO, HI) { \
    LO += u2h((((W) & 0x007f007fu) << 7) | (((W) & 0x00800080u) << 8)); \
    HI += u2h((((W) & 0x7f007f00u) >> 1) | ((W) & 0x80008000u)); }

// ---- phase 1 + weight conversions in one launch ----
// blocks [0, NPB): edge partition; [NPB, NPB+48): wt1/wt2; rest: D3 transpose
__global__ __launch_bounds__(512) void k_part(const int* __restrict__ src, const int* __restrict__ dst,
        int* __restrict__ tmp, int* __restrict__ scanhist,
        const float* __restrict__ W1, const float* __restrict__ W2, const float* __restrict__ D3,
        unsigned short* __restrict__ wt1, unsigned short* __restrict__ wt2,
        unsigned short* __restrict__ wt3t) {
    int t = threadIdx.x;
    if (blockIdx.x >= NPB) {
        int blk2 = blockIdx.x - NPB;
        if (blk2 < 48) {
            int i = blk2 * 512 + t;
            if (i < 8192) {                      // wt1: [128][64] f16, transposed
                int n = i >> 6, k = i & 63;
                wt1[i] = (unsigned short)__half_as_ushort(__float2half(W1[k * 128 + n]));
            } else {                             // wt2: [128][128] bf16, transposed
                int e = i - 8192;
                int n = e >> 7, k = e & 127;
                wt2[e] = f2bf(W2[k * 128 + n]);
            }
        } else {
            __shared__ float tile[32][33];
            int bb = blk2 - 48;                  // 0..1015
            int n0 = (bb % 254) * 32, k0 = (bb / 254) * 32;
            for (int i = t; i < 1024; i += 512) {
                int kk = i >> 5, nn = i & 31;
                tile[kk][nn] = D3[(long)(k0 + kk) * OUTS + n0 + nn];
            }
            __syncthreads();
            for (int i = t; i < 1024; i += 512) {
                int nn = i >> 5, kk = i & 31;
                wt3t[(long)(n0 + nn) * 128 + k0 + kk] =
                    (unsigned short)__half_as_ushort(__float2half(tile[kk][nn]));
            }
        }
        return;
    }
    __shared__ int hist[NB2], cur[NB2], scan[256];
    int p = blockIdx.x;
    int e0 = p * CHUNK;
    int e1 = min(e0 + CHUNK, NE);
    for (int i = t; i < NB2; i += 512) hist[i] = 0;
    __syncthreads();
    for (int e = e0 + t; e < e1; e += 512)
        atomicAdd(&hist[dst[e] >> 9], 1);
    __syncthreads();
    int h = 0;
    if (t < 256) { h = (t < NB2) ? hist[t] : 0; scan[t] = h; }
    __syncthreads();
    for (int off = 1; off < 256; off <<= 1) {
        int v = (t < 256 && t >= off) ? scan[t - off] : 0;
        __syncthreads();
        if (t < 256) scan[t] += v;
        __syncthreads();
    }
    if (t < NB2) {
        int excl = scan[t] - h;
        cur[t] = excl;
        scanhist[p * (NB2 + 1) + t] = excl;
    }
    if (t == 0) scanhist[p * (NB2 + 1) + NB2] = e1 - e0;
    __syncthreads();
    for (int e = e0 + t; e < e1; e += 512) {
        int d = dst[e];
        int b = d >> 9;
        int r = atomicAdd(&cur[b], 1);          // LDS atomic only
        tmp[e0 + r] = (src[e] << 9) | (d & 511);
    }
}

// ---- block 0: bucket totals + scan -> bucketbase; blocks 1..: segment ends ----
__global__ __launch_bounds__(256) void k_btotseg(const int* __restrict__ scanhist,
        int* __restrict__ bucketbase, const int* __restrict__ batch, int* __restrict__ seg_end) {
    if (blockIdx.x == 0) {
        __shared__ int sc[256];
        int b = threadIdx.x;
        int tot = 0;
        if (b < NB2) {
            for (int p = 0; p < NPB; ++p)
                tot += scanhist[p * (NB2 + 1) + b + 1] - scanhist[p * (NB2 + 1) + b];
        }
        sc[b] = tot;
        __syncthreads();
        for (int off = 1; off < 256; off <<= 1) {
            int v = (b >= off) ? sc[b - off] : 0;
            __syncthreads();
            sc[b] += v;
            __syncthreads();
        }
        if (b < NB2) bucketbase[b] = sc[b] - tot;
    } else {
        int i = (blockIdx.x - 1) * 256 + threadIdx.x;
        if (i >= NN) return;
        int b = batch[i];
        int bn = (i == NN - 1) ? NG : batch[i + 1];
        for (int g = b; g < bn; ++g) seg_end[g] = i + 1;
        if (i == 0) {
            for (int g = 0; g < b; ++g) seg_end[g] = 0;
        }
    }
}

// ---- phase 2: per-bucket count+scan+place; emits cnti/rowptr/dinv/colidx AND u1b = fp8(x*dinv) ----
__global__ __launch_bounds__(1024) void k_fill2(const int* __restrict__ bucketbase,
        const int* __restrict__ scanhist, const int* __restrict__ tmp,
        int* __restrict__ colidx, int* __restrict__ cnti, int* __restrict__ rowptr,
        float* __restrict__ dinv, const float* __restrict__ x, unsigned* __restrict__ u1b) {
    __shared__ int lc[512], rb[512], sc[256];
    __shared__ float ldv[512];
    int b = blockIdx.x, t = threadIdx.x;
    int n0 = b << 9;
    if (t < 512) lc[t] = 0;
    __syncthreads();
    int w = t >> 6, lane = t & 63;              // w in 0..15
    // count phase
    for (int p = w; p < NPB; p += 16) {
        int s0 = scanhist[p * (NB2 + 1) + b];
        int s1 = scanhist[p * (NB2 + 1) + b + 1];
        int base = p * CHUNK;
        for (int i = s0 + lane; i < s1; i += 64)
            atomicAdd(&lc[tmp[base + i] & 511], 1);
    }
    __syncthreads();
    // scan 512 via 256 pair-partials
    int v0 = 0, v1 = 0, s = 0;
    if (t < 256) { v0 = lc[2 * t]; v1 = lc[2 * t + 1]; s = v0 + v1; sc[t] = s; }
    __syncthreads();
    for (int off = 1; off < 256; off <<= 1) {
        int xv = (t < 256 && t >= off) ? sc[t - off] : 0;
        __syncthreads();
        if (t < 256) sc[t] += xv;
        __syncthreads();
    }
    if (t < 256) {
        int excl = sc[t] - s;
        int base0 = bucketbase[b];
        rb[2 * t] = base0 + excl;
        rb[2 * t + 1] = base0 + excl + v0;
        float dv0 = rsqrtf((float)v0 + 1.0f);
        float dv1 = rsqrtf((float)v1 + 1.0f);
        ldv[2 * t] = dv0;
        ldv[2 * t + 1] = dv1;
        int node0 = n0 + 2 * t;
        if (node0 < NN) {
            cnti[node0] = v0;
            rowptr[node0] = base0 + excl;
            dinv[node0] = dv0;
        }
        if (node0 + 1 < NN) {
            cnti[node0 + 1] = v1;
            rowptr[node0 + 1] = base0 + excl + v0;
            dinv[node0 + 1] = dv1;
        }
    }
    __syncthreads();
    if (t < 512) lc[t] = 0;
    __syncthreads();
    // place phase
    for (int p = w; p < NPB; p += 16) {
        int s0 = scanhist[p * (NB2 + 1) + b];
        int s1 = scanhist[p * (NB2 + 1) + b + 1];
        int base = p * CHUNK;
        for (int i = s0 + lane; i < s1; i += 64) {
            int v = tmp[base + i];
            int dl = v & 511;
            int pos = atomicAdd(&lc[dl], 1);    // LDS atomic only
            colidx[rb[dl] + pos] = v >> 9;
        }
    }
    // x-scale phase: u1b[node][c] = fp8s(x*dinv), 16 uints (64ch) per node
    for (int i = t; i < 512 * 16; i += 1024) {
        int local = i >> 4, c = i & 15;
        int node = n0 + local;
        if (node >= NN) continue;
        float4 xv = *(const float4*)&x[(long)node * 64 + c * 4];
        float d = ldv[local];
        unsigned o = f2fp8s(xv.x * d) | (f2fp8s(xv.y * d) << 8)
                   | (f2fp8s(xv.z * d) << 16) | (f2fp8s(xv.w * d) << 24);
        u1b[node * 16 + c] = o;
    }
}

// ---- gather1: s1 = f16(dinv_n * (u1[n] + sum u1[src])), 64ch signed fp8 in ----
// 4 lanes/node, uint4 (16ch) per lane, 8-deep unroll (128B in flight/lane)
__global__ __launch_bounds__(256) void k_gather1(const int* __restrict__ rowptr,
        const int* __restrict__ cnti, const int* __restrict__ colidx,
        const unsigned* __restrict__ u, const float* __restrict__ dinv,
        unsigned* __restrict__ s1) {
    int node = blockIdx.x * 64 + (threadIdx.x >> 2);
    if (node >= NN) return;
    int lane = threadIdx.x & 3;
    const uint4* uf = (const uint4*)u;          // row = 4 uint4 (64 fp8)
    uint4 self = uf[node * 4 + lane];
    f16x2 z = {(_Float16)0.f, (_Float16)0.f};
    f16x2 la0 = z, ha0 = z, la1 = z, ha1 = z, la2 = z, ha2 = z, la3 = z, ha3 = z;
    f16x2 lb0 = z, hb0 = z, lb1 = z, hb1 = z, lb2 = z, hb2 = z, lb3 = z, hb3 = z;
    DECOS(self.x, la0, ha0) DECOS(self.y, la1, ha1) DECOS(self.z, la2, ha2) DECOS(self.w, la3, ha3)
    int n = cnti[node];
    const int* ci = colidx + rowptr[node];
    int j = 0;
    for (; j + 8 <= n; j += 8) {
        uint4 v0 = uf[ci[j] * 4 + lane];
        uint4 v1 = uf[ci[j + 1] * 4 + lane];
        uint4 v2 = uf[ci[j + 2] * 4 + lane];
        uint4 v3 = uf[ci[j + 3] * 4 + lane];
        uint4 v4 = uf[ci[j + 4] * 4 + lane];
        uint4 v5 = uf[ci[j + 5] * 4 + lane];
        uint4 v6 = uf[ci[j + 6] * 4 + lane];
        uint4 v7 = uf[ci[j + 7] * 4 + lane];
        DECOS(v0.x, la0, ha0) DECOS(v0.y, la1, ha1) DECOS(v0.z, la2, ha2) DECOS(v0.w, la3, ha3)
        DECOS(v1.x, lb0, hb0) DECOS(v1.y, lb1, hb1) DECOS(v1.z, lb2, hb2) DECOS(v1.w, lb3, hb3)
        DECOS(v2.x, la0, ha0) DECOS(v2.y, la1, ha1) DECOS(v2.z, la2, ha2) DECOS(v2.w, la3, ha3)
        DECOS(v3.x, lb0, hb0) DECOS(v3.y, lb1, hb1) DECOS(v3.z, lb2, hb2) DECOS(v3.w, lb3, hb3)
        DECOS(v4.x, la0, ha0) DECOS(v4.y, la1, ha1) DECOS(v4.z, la2, ha2) DECOS(v4.w, la3, ha3)
        DECOS(v5.x, lb0, hb0) DECOS(v5.y, lb1, hb1) DECOS(v5.z, lb2, hb2) DECOS(v5.w, lb3, hb3)
        DECOS(v6.x, la0, ha0) DECOS(v6.y, la1, ha1) DECOS(v6.z, la2, ha2) DECOS(v6.w, la3, ha3)
        DECOS(v7.x, lb0, hb0) DECOS(v7.y, lb1, hb1) DECOS(v7.z, lb2, hb2) DECOS(v7.w, lb3, hb3)
    }
    if (j + 4 <= n) {
        uint4 v0 = uf[ci[j] * 4 + lane];
        uint4 v1 = uf[ci[j + 1] * 4 + lane];
        uint4 v2 = uf[ci[j + 2] * 4 + lane];
        uint4 v3 = uf[ci[j + 3] * 4 + lane];
        DECOS(v0.x, la0, ha0) DECOS(v0.y, la1, ha1) DECOS(v0.z, la2, ha2) DECOS(v0.w, la3, ha3)
        DECOS(v1.x, lb0, hb0) DECOS(v1.y, lb1, hb1) DECOS(v1.z, lb2, hb2) DECOS(v1.w, lb3, hb3)
        DECOS(v2.x, la0, ha0) DECOS(v2.y, la1, ha1) DECOS(v2.z, la2, ha2) DECOS(v2.w, la3, ha3)
        DECOS(v3.x, lb0, hb0) DECOS(v3.y, lb1, hb1) DECOS(v3.z, lb2, hb2) DECOS(v3.w, lb3, hb3)
        j += 4;
    }
    for (; j < n; ++j) {
        uint4 va = uf[ci[j] * 4 + lane];
        DECOS(va.x, la0, ha0) DECOS(va.y, la1, ha1) DECOS(va.z, la2, ha2) DECOS(va.w, la3, ha3)
    }
    la0 += lb0; ha0 += hb0; la1 += lb1; ha1 += hb1;
    la2 += lb2; ha2 += hb2; la3 += lb3; ha3 += hb3;
    float d = dinv[node] * 256.0f;              // *256 decode scale
    uint4 o1, o2;
    o1.x = cvt_pkrtz_u((float)la0[0] * d, (float)ha0[0] * d);
    o1.y = cvt_pkrtz_u((float)la0[1] * d, (float)ha0[1] * d);
    o1.z = cvt_pkrtz_u((float)la1[0] * d, (float)ha1[0] * d);
    o1.w = cvt_pkrtz_u((float)la1[1] * d, (float)ha1[1] * d);
    o2.x = cvt_pkrtz_u((float)la2[0] * d, (float)ha2[0] * d);
    o2.y = cvt_pkrtz_u((float)la2[1] * d, (float)ha2[1] * d);
    o2.z = cvt_pkrtz_u((float)la3[0] * d, (float)ha3[0] * d);
    o2.w = cvt_pkrtz_u((float)la3[1] * d, (float)ha3[1] * d);
    *(uint4*)&s1[node * 32 + lane * 8] = o1;
    *(uint4*)&s1[node * 32 + lane * 8 + 4] = o2;
}

// ---- gather2: s2 = bf16(16*dinv_n * sum fp8rows), 128ch fp8 (relu'd, unsigned) ----
// 8 lanes/node, uint4 (16ch) per lane, 8-deep unroll
__global__ __launch_bounds__(256) void k_gather2(const int* __restrict__ rowptr,
        const int* __restrict__ cnti, const int* __restrict__ colidx,
        const unsigned* __restrict__ u, const float* __restrict__ dinv,
        unsigned* __restrict__ s2) {
    int node = blockIdx.x * 32 + (threadIdx.x >> 3);
    int lane = threadIdx.x & 7;
    const uint4* uf = (const uint4*)u;          // row = 8 uint4 (128 fp8)
    uint4 self = uf[node * 8 + lane];
    f16x2 z = {(_Float16)0.f, (_Float16)0.f};
    f16x2 la0 = z, ha0 = z, la1 = z, ha1 = z, la2 = z, ha2 = z, la3 = z, ha3 = z;
    f16x2 lb0 = z, hb0 = z, lb1 = z, hb1 = z, lb2 = z, hb2 = z, lb3 = z, hb3 = z;
    DECO(self.x, la0, ha0) DECO(self.y, la1, ha1) DECO(self.z, la2, ha2) DECO(self.w, la3, ha3)
    int n = cnti[node];
    const int* ci = colidx + rowptr[node];
    int j = 0;
    for (; j + 8 <= n; j += 8) {
        uint4 v0 = uf[ci[j] * 8 + lane];
        uint4 v1 = uf[ci[j + 1] * 8 + lane];
        uint4 v2 = uf[ci[j + 2] * 8 + lane];
        uint4 v3 = uf[ci[j + 3] * 8 + lane];
        uint4 v4 = uf[ci[j + 4] * 8 + lane];
        uint4 v5 = uf[ci[j + 5] * 8 + lane];
        uint4 v6 = uf[ci[j + 6] * 8 + lane];
        uint4 v7 = uf[ci[j + 7] * 8 + lane];
        DECO(v0.x, la0, ha0) DECO(v0.y, la1, ha1) DECO(v0.z, la2, ha2) DECO(v0.w, la3, ha3)
        DECO(v1.x, lb0, hb0) DECO(v1.y, lb1, hb1) DECO(v1.z, lb2, hb2) DECO(v1.w, lb3, hb3)
        DECO(v2.x, la0, ha0) DECO(v2.y, la1, ha1) DECO(v2.z, la2, ha2) DECO(v2.w, la3, ha3)
        DECO(v3.x, lb0, hb0) DECO(v3.y, lb1, hb1) DECO(v3.z, lb2, hb2) DECO(v3.w, lb3, hb3)
        DECO(v4.x, la0, ha0) DECO(v4.y, la1, ha1) DECO(v4.z, la2, ha2) DECO(v4.w, la3, ha3)
        DECO(v5.x, lb0, hb0) DECO(v5.y, lb1, hb1) DECO(v5.z, lb2, hb2) DECO(v5.w, lb3, hb3)
        DECO(v6.x, la0, ha0) DECO(v6.y, la1, ha1) DECO(v6.z, la2, ha2) DECO(v6.w, la3, ha3)
        DECO(v7.x, lb0, hb0) DECO(v7.y, lb1, hb1) DECO(v7.z, lb2, hb2) DECO(v7.w, lb3, hb3)
    }
    if (j + 4 <= n) {
        uint4 v0 = uf[ci[j] * 8 + lane];
        uint4 v1 = uf[ci[j + 1] * 8 + lane];
        uint4 v2 = uf[ci[j + 2] * 8 + lane];
        uint4 v3 = uf[ci[j + 3] * 8 + lane];
        DECO(v0.x, la0, ha0) DECO(v0.y, la1, ha1) DECO(v0.z, la2, ha2) DECO(v0.w, la3, ha3)
        DECO(v1.x, lb0, hb0) DECO(v1.y, lb1, hb1) DECO(v1.z, lb2, hb2) DECO(v1.w, lb3, hb3)
        DECO(v2.x, la0, ha0) DECO(v2.y, la1, ha1) DECO(v2.z, la2, ha2) DECO(v2.w, la3, ha3)
        DECO(v3.x, lb0, hb0) DECO(v3.y, lb1, hb1) DECO(v3.z, lb2, hb2) DECO(v3.w, lb3, hb3)
        j += 4;
    }
    for (; j < n; ++j) {
        uint4 va = uf[ci[j] * 8 + lane];
        DECO(va.x, la0, ha0) DECO(va.y, la1, ha1) DECO(va.z, la2, ha2) DECO(va.w, la3, ha3)
    }
    la0 += lb0; ha0 += hb0; la1 += lb1; ha1 += hb1;
    la2 += lb2; ha2 += hb2; la3 += lb3; ha3 += hb3;
    float d = dinv[node] * 16.0f;   // *256 (decode) / 16 (encode scale)
    uint4 o1, o2;
    o1.x = pack_bf16x2((float)la0[0] * d, (float)ha0[0] * d);
    o1.y = pack_bf16x2((float)la0[1] * d, (float)ha0[1] * d);
    o1.z = pack_bf16x2((float)la1[0] * d, (float)ha1[0] * d);
    o1.w = pack_bf16x2((float)la1[1] * d, (float)ha1[1] * d);
    o2.x = pack_bf16x2((float)la2[0] * d, (float)ha2[0] * d);
    o2.y = pack_bf16x2((float)la2[1] * d, (float)ha2[1] * d);
    o2.z = pack_bf16x2((float)la3[0] * d, (float)ha3[0] * d);
    o2.w = pack_bf16x2((float)la3[1] * d, (float)ha3[1] * d);
    *(uint4*)&s2[node * 64 + lane * 8] = o1;
    *(uint4*)&s2[node * 64 + lane * 8 + 4] = o2;
}

// ---- MFMA GEMM: h = relu(A@W + bias); AF16: f16 inputs; EPI 0: out fp8(16*dinv*h); 1: bf16 ----
template<int K, int EPI, int AF16>
__global__ __launch_bounds__(256) void k_gemm_mfma(const unsigned short* __restrict__ Ab,
        const unsigned short* __restrict__ wt, const float* __restrict__ dinv,
        const float* __restrict__ bias, void* __restrict__ outp) {
    constexpr int KS = K / 32;
    constexpr int SLOTS = K / 8;
    __shared__ __align__(16) unsigned short wlds[128 * K];
    char* lb = (char*)wlds;
    for (int c = threadIdx.x; c < 128 * SLOTS; c += 256) {
        int n = c / SLOTS, s = c - n * SLOTS;
        *(uint4*)(lb + n * (2 * K) + ((s ^ (n & 7)) << 4)) = *(const uint4*)(wt + c * 8);
    }
    __syncthreads();
    int lane = threadIdx.x & 63;
    int w = threadIdx.x >> 6;
    int r0 = blockIdx.x * 64 + w * 16;
    int arow = r0 + (lane & 15);
    if (arow >= NN) arow = NN - 1;
    bf16x8 af[KS];
    #pragma unroll
    for (int ks = 0; ks < KS; ++ks)
        af[ks] = *(const bf16x8*)&Ab[(long)arow * K + ks * 32 + (lane >> 4) * 8];
    f32x4 acc[8];
    #pragma unroll
    for (int t = 0; t < 8; ++t) acc[t] = (f32x4){0.f, 0.f, 0.f, 0.f};
    #pragma unroll
    for (int ks = 0; ks < KS; ++ks) {
        #pragma unroll
        for (int t = 0; t < 8; ++t) {
            int n = t * 16 + (lane & 15);
            int slot = ks * 4 + (lane >> 4);
            bf16x8 braw = *(const bf16x8*)(lb + n * (2 * K) + ((slot ^ (n & 7)) << 4));
            if constexpr (AF16) {
                union { bf16x8 r; f16x8 h; } ca, cb;
                ca.r = af[ks]; cb.r = braw;
                acc[t] = __builtin_amdgcn_mfma_f32_16x16x32_f16(ca.h, cb.h, acc[t], 0, 0, 0);
            } else {
                acc[t] = __builtin_amdgcn_mfma_f32_16x16x32_bf16(af[ks], braw, acc[t], 0, 0, 0);
            }
        }
    }
    float bv[8];
    #pragma unroll
    for (int t = 0; t < 8; ++t) bv[t] = bias[t * 16 + (lane & 15)];
    #pragma unroll
    for (int r = 0; r < 4; ++r) {
        long row = r0 + (lane >> 4) * 4 + r;
        if (row >= NN) continue;
        float d = dinv[row];
        #pragma unroll
        for (int t = 0; t < 8; ++t) {
            float val = fmaxf(acc[t][r] + bv[t], 0.f);
            int col = t * 16 + (lane & 15);
            if (EPI == 0)
                ((unsigned char*)outp)[row * 128 + col] = (unsigned char)f2fp8(val * (16.0f * d));
            else
                ((unsigned short*)outp)[row * 128 + col] = f2bf(val);
        }
    }
}

// ---- fused: segmented mean pool + mu/lv/z + 2 MLP layers; one block (256 thr) per graph ----
__global__ __launch_bounds__(256) void k_pooldec(const unsigned* __restrict__ h,
        const int* __restrict__ seg_end,
        const float* __restrict__ Wmu, const float* __restrict__ bmu,
        const float* __restrict__ Wlv, const float* __restrict__ blv,
        const float* __restrict__ eps,
        const float* __restrict__ D1, const float* __restrict__ d1,
        const float* __restrict__ D2, const float* __restrict__ d2,
        float* __restrict__ mu_o, float* __restrict__ lv_o,
        unsigned short* __restrict__ p2out) {
    __shared__ float part[3][128];
    __shared__ float row[128], mlv[128], zr[64], p1[128];
    int g = blockIdx.x;
    int w = threadIdx.x >> 6, t64 = threadIdx.x & 63;
    int s = (g == 0) ? 0 : seg_end[g - 1];
    int e = seg_end[g];
    float a0 = 0.f, a1 = 0.f;
    for (int i = s + w; i < e; i += 4) {
        unsigned u = h[(long)i * 64 + t64];
        a0 += __uint_as_float(u << 16);
        a1 += __uint_as_float(u & 0xffff0000u);
    }
    if (w) { part[w - 1][t64 * 2] = a0; part[w - 1][t64 * 2 + 1] = a1; }
    __syncthreads();
    if (w == 0) {
        a0 += part[0][t64 * 2] + part[1][t64 * 2] + part[2][t64 * 2];
        a1 += part[0][t64 * 2 + 1] + part[1][t64 * 2 + 1] + part[2][t64 * 2 + 1];
        float inv = (e > s) ? 1.0f / (float)(e - s) : 0.f;
        row[t64 * 2] = a0 * inv;
        row[t64 * 2 + 1] = a1 * inv;
    }
    __syncthreads();
    int t = threadIdx.x;
    if (t < 64) {
        float acc = bmu[t];
        for (int k = 0; k < 128; ++k) acc += row[k] * Wmu[k * 64 + t];
        mlv[t] = acc;
    } else if (t < 128) {
        int t2 = t - 64;
        float acc = blv[t2];
        for (int k = 0; k < 128; ++k) acc += row[k] * Wlv[k * 64 + t2];
        mlv[64 + t2] = acc;
    }
    __syncthreads();
    if (t < 64) {
        float mu = mlv[t], lv = mlv[64 + t];
        mu_o[g * 64 + t] = mu;
        lv_o[g * 64 + t] = lv;
        zr[t] = mu + eps[g * 64 + t] * expf(0.5f * lv);
    }
    __syncthreads();
    if (t < 128) {
        float acc = d1[t];
        for (int k = 0; k < 64; ++k) acc += zr[k] * D1[k * 128 + t];
        p1[t] = fmaxf(acc, 0.f);
    }
    __syncthreads();
    if (t < 128) {
        float acc = d2[t];
        for (int k = 0; k < 128; ++k) acc += p1[k] * D2[k * 128 + t];
        p2out[g * 128 + t] = (unsigned short)__half_as_ushort(__float2half(fmaxf(acc, 0.f)));
    }
}

// ---- probs = sigmoid(p2 @ D3 + d3) via MFMA f16; no LDS; 64x64 tiles ----
__global__ __launch_bounds__(256) void k_dec3m(const unsigned short* __restrict__ Ab,
        const unsigned short* __restrict__ Wt, const float* __restrict__ b,
        float* __restrict__ out) {
    int lane = threadIdx.x & 63;
    int w = threadIdx.x >> 6;
    int r0 = blockIdx.x * 64 + w * 16;          // m in 0..511
    int c0 = blockIdx.y * 64;                    // n in 0..8127
    int arow = r0 + (lane & 15);
    f16x8 af[4];
    #pragma unroll
    for (int ks = 0; ks < 4; ++ks) {
        union { bf16x8 r; f16x8 h; } ca;
        ca.r = *(const bf16x8*)&Ab[arow * 128 + ks * 32 + (lane >> 4) * 8];
        af[ks] = ca.h;
    }
    f32x4 acc[4];
    #pragma unroll
    for (int nt = 0; nt < 4; ++nt) acc[nt] = (f32x4){0.f, 0.f, 0.f, 0.f};
    #pragma unroll
    for (int nt = 0; nt < 4; ++nt) {
        long n = c0 + nt * 16 + (lane & 15);
        #pragma unroll
        for (int ks = 0; ks < 4; ++ks) {
            union { bf16x8 r; f16x8 h; } cb;
            cb.r = *(const bf16x8*)&Wt[n * 128 + ks * 32 + (lane >> 4) * 8];
            acc[nt] = __builtin_amdgcn_mfma_f32_16x16x32_f16(af[ks], cb.h, acc[nt], 0, 0, 0);
        }
    }
    #pragma unroll
    for (int nt = 0; nt < 4; ++nt) {
        int col = c0 + nt * 16 + (lane & 15);
        float bias = b[col];
        #pragma unroll
        for (int r = 0; r < 4; ++r) {
            int row = r0 + (lane >> 4) * 4 + r;
            float v = acc[nt][r] + bias;
            out[(long)row * OUTS + col] = 1.f / (1.f + expf(-v));
        }
    }
}

// ---- build symmetric adjacency ----
__global__ __launch_bounds__(256) void k_adj(const float* __restrict__ probs, float* __restrict__ adj) {
    int t = blockIdx.x * 256 + threadIdx.x;
    int g = t >> 12;
    int rem = t & 4095;
    int r = rem >> 5;
    int c0 = (rem & 31) * 4;
    const float* pg = &probs[g * OUTS];
    float4 o;
    float* op = (float*)&o;
    #pragma unroll
    for (int j = 0; j < 4; ++j) {
        int c = c0 + j;
        if (c == r) { op[j] = 0.f; continue; }
        int a = c < r ? c : r;
        int b = c < r ? r : c;
        int k = a * (255 - a) / 2 + (b - a - 1);
        op[j] = pg[k];
    }
    *(float4*)&adj[(long)t * 4] = o;
}

extern "C" void kernel_launch(void* const* d_in, const int* in_sizes, int n_in,
                              void* d_out, int out_size, void* d_ws, size_t ws_size,
                              hipStream_t stream) {
    const float* x   = (const float*)d_in[0];
    const int*   ei  = (const int*)d_in[1];
    const int* batch = (const int*)d_in[2];
    const float* eps = (const float*)d_in[3];
    const float* W1  = (const float*)d_in[4];
    const float* b1  = (const float*)d_in[5];
    const float* W2  = (const float*)d_in[6];
    const float* b2  = (const float*)d_in[7];
    const float* Wmu = (const float*)d_in[8];
    const float* bmu = (const float*)d_in[9];
    const float* Wlv = (const float*)d_in[10];
    const float* blv = (const float*)d_in[11];
    const float* D1  = (const float*)d_in[12];
    const float* d1  = (const float*)d_in[13];
    const float* D2  = (const float*)d_in[14];
    const float* d2  = (const float*)d_in[15];
    const float* D3  = (const float*)d_in[16];
    const float* d3  = (const float*)d_in[17];

    const int* esrc = ei;
    const int* edst = ei + NE;

    float* out  = (float*)d_out;
    float* mu_o = out + 8388608;
    float* lv_o = mu_o + 32768;

    // --- CSR + small scratch in d_out (region fully overwritten by k_adj at the end) ---
    int*   colidx   = (int*)out;                  // 1,600,000
    int*   cnti     = colidx + 1600000;           // 100,000
    int*   rowptr   = cnti + 100000;              // 100,000
    int*   seg_end  = rowptr + 100000;            // 512
    float* dinv     = (float*)(seg_end + 512);    // 100,000
    int*   scanhist = (int*)(dinv + 100000);      // 196*197 = 38,612
    int*   bucketbase = scanhist + 38612;         // 196
    unsigned short* wt3t = (unsigned short*)(bucketbase + 256);  // 1,040,384 u16 (ends ~2.46M floats << 8.39M)

    // --- ws layout (float-unit offsets) ---
    float* ws = (float*)d_ws;
    unsigned* u1b = (unsigned*)ws;                         // 1.6M uints (fp8, 16/row)
    unsigned* s1u = (unsigned*)(ws + 3200000);             // 3.2M uints (f16x2)
    unsigned char* u2b = (unsigned char*)(ws + 6400000);   // 12.8M bytes (fp8)
    unsigned* s2u = (unsigned*)(ws + 9600000);             // 6.4M uints (bf16x2)
    unsigned* h2b = (unsigned*)(ws + 16000000);            // 6.4M uints (bf16x2)
    unsigned short* wt1 = (unsigned short*)(ws + 22400000);   // 8192 u16 (f16)
    unsigned short* wt2 = wt1 + 8192;                         // 16384 u16 (bf16)
    int* tmp = (int*)(ws + 22420000);                      // 1.6M+ ints
    // decoder scratch aliases u1b/s1u (dead by then)
    unsigned short* p2b = (unsigned short*)ws;             // 65,536 u16
    float* probs = ws + 65536;                             // 4.16M floats (s1u dead by then)

    // ---- CSR build + weight conversions (one launch), zero global atomics ----
    k_part<<<NPB + 48 + 1016, 512, 0, stream>>>(esrc, edst, tmp, scanhist,
                                                W1, W2, D3, wt1, wt2, wt3t);
    k_btotseg<<<392, 256, 0, stream>>>(scanhist, bucketbase, batch, seg_end);
    k_fill2<<<NB2, 1024, 0, stream>>>(bucketbase, scanhist, tmp, colidx, cnti, rowptr,
                                      dinv, x, u1b);

    // ---- conv1 (signed-fp8 gather in 64-ch x-space, then f16 MFMA GEMM -> fp8) ----
    k_gather1<<<1563, 256, 0, stream>>>(rowptr, cnti, colidx, u1b, dinv, s1u);
    k_gemm_mfma<64, 0, 1><<<1563, 256, 0, stream>>>((const unsigned short*)s1u, wt1, dinv, b1, u2b);

    // ---- conv2 (fp8 packed-decode gather, then bf16 MFMA GEMM) ----
    k_gather2<<<3125, 256, 0, stream>>>(rowptr, cnti, colidx, (const unsigned*)u2b, dinv, s2u);
    k_gemm_mfma<128, 1, 0><<<1563, 256, 0, stream>>>((const unsigned short*)s2u, wt2, dinv, b2, h2b);

    // ---- fused pool + decoder head ----
    k_pooldec<<<NG, 256, 0, stream>>>(h2b, seg_end, Wmu, bmu, Wlv, blv, eps,
                                      D1, d1, D2, d2, mu_o, lv_o, p2b);

    // ---- MFMA decoder output + adjacency ----
    dim3 g3(8, 127);
    k_dec3m<<<g3, 256, 0, stream>>>(p2b, wt3t, d3, probs);
    k_adj<<<8192, 256, 0, stream>>>(probs, out);
}